// Round 3
// baseline (1356.653 us; speedup 1.0000x reference)
//
#include <hip/hip_runtime.h>
#include <hip/hip_bf16.h>

typedef unsigned short u16;
typedef __attribute__((ext_vector_type(8))) short sh8;     // 8 x bf16 (4 VGPRs)
typedef __attribute__((ext_vector_type(4))) float f32x4;   // MFMA accum

#define NV 8192
#define NG 4096
#define NE 65536
#define NSLICE 32

__device__ __forceinline__ u16 f2bf(float f) {
  __hip_bfloat16 h = __float2bfloat16(f);
  return __builtin_bit_cast(u16, h);
}

// ---------------- setup fills ----------------
__global__ void k_fill4(float* __restrict__ deg_v, float* __restrict__ deg_g,
                        float* __restrict__ deg_e, int* __restrict__ cnt) {
  int i = blockIdx.x * 256 + threadIdx.x;
  if (i < NV) deg_v[i] = 1.f;
  int j = i - NV;
  if (j >= 0 && j < NG) deg_g[j] = 1.f;
  j -= NG;
  if (j >= 0 && j < NG) deg_e[j] = 1.f;
  j -= NG;
  if (j >= 0 && j < NG) cnt[j] = 0;
}

// ---------------- Wb build: W = (d<8)?exp(-d/4):0, row/col sums, optional WbT
__global__ __launch_bounds__(256) void k_wb_build(
    const float* __restrict__ vert, const float* __restrict__ gpos,
    u16* __restrict__ Wb, u16* __restrict__ WbT,
    float* __restrict__ deg_v, float* __restrict__ deg_g) {
  __shared__ float lv[192], lg[192], colp[256];
  __shared__ float tile[64][65];
  int t = threadIdx.x;
  int v0 = blockIdx.x * 64, g0 = blockIdx.y * 64;
  if (t < 192) { lv[t] = vert[(size_t)v0 * 3 + t]; lg[t] = gpos[(size_t)g0 * 3 + t]; }
  __syncthreads();
  int w = t >> 6, lane = t & 63;
  float gx_ = lg[lane * 3], gy_ = lg[lane * 3 + 1], gz_ = lg[lane * 3 + 2];
  float csum = 0.f;
  #pragma unroll 4
  for (int s = 0; s < 16; s++) {
    int vl = w + 4 * s;
    float dx = lv[vl * 3] - gx_, dy = lv[vl * 3 + 1] - gy_, dz = lv[vl * 3 + 2] - gz_;
    float d = sqrtf(dx * dx + dy * dy + dz * dz);
    float W = (d < 8.0f) ? expf(d * -0.25f) : 0.f;
    Wb[(size_t)(v0 + vl) * NG + g0 + lane] = f2bf(W);
    tile[vl][lane] = W;
    csum += W;
  }
  colp[t] = csum;
  __syncthreads();
  // row sums: 4 threads per row
  int r = t >> 2, q = t & 3;
  float rs = 0.f;
  #pragma unroll
  for (int j = 0; j < 16; j++) rs += tile[r][q * 16 + j];
  rs += __shfl_xor(rs, 1);
  rs += __shfl_xor(rs, 2);
  if (q == 0) atomicAdd(&deg_v[v0 + r], rs);
  if (w == 0) {
    float tot = colp[lane] + colp[64 + lane] + colp[128 + lane] + colp[192 + lane];
    atomicAdd(&deg_g[g0 + lane], tot);
  }
  if (WbT != nullptr) {
    #pragma unroll
    for (int j = 0; j < 2; j++) {
      int idx = j * 256 + t;
      int g = idx >> 3, v8 = (idx & 7) * 8;
      u16 pk[8];
      #pragma unroll
      for (int qq = 0; qq < 8; qq++) pk[qq] = f2bf(tile[v8 + qq][g]);
      *(uint4*)&WbT[(size_t)(g0 + g) * NV + v0 + v8] = *(uint4*)pk;
    }
  }
}

// all three recips in one launch
__global__ void k_recips(const float* __restrict__ deg_v, float* __restrict__ inv_v,
                         float* __restrict__ rs_v, const float* __restrict__ deg_g,
                         float* __restrict__ inv_g, float* __restrict__ rs_g,
                         const float* __restrict__ deg_e, float* __restrict__ inv_e,
                         float* __restrict__ rs_e) {
  int i = blockIdx.x * 256 + threadIdx.x;
  if (i < NV) { float d = deg_v[i]; inv_v[i] = 1.f / d; rs_v[i] = 1.f / sqrtf(d); }
  else if (i < NV + NG) {
    int j = i - NV; float d = deg_g[j]; inv_g[j] = 1.f / d; rs_g[j] = 1.f / sqrtf(d);
  } else if (i < NV + 2 * NG) {
    int j = i - NV - NG; float d = deg_e[j]; inv_e[j] = 1.f / d; rs_e[j] = 1.f / sqrtf(d);
  }
}

// ---------------- edge preprocessing (CSR) ----------------
__global__ void k_edge_prep(const int* __restrict__ eidx, const float* __restrict__ ew,
                            float* __restrict__ deg_e, int* __restrict__ cnt) {
  int e = blockIdx.x * 256 + threadIdx.x;
  if (e < NE) { int d = eidx[NE + e]; atomicAdd(&deg_e[d], ew[e]); atomicAdd(&cnt[d], 1); }
}

__global__ __launch_bounds__(1024) void k_scan(const int* __restrict__ cnt,
    int* __restrict__ row_ptr, int* __restrict__ cursor) {
  __shared__ int buf0[1024], buf1[1024];
  int t = threadIdx.x;
  int b = t * 4;
  int c0 = cnt[b], c1 = cnt[b + 1], c2 = cnt[b + 2], c3 = cnt[b + 3];
  int s = c0 + c1 + c2 + c3;
  buf0[t] = s;
  __syncthreads();
  int* src = buf0; int* dst = buf1;
  for (int off = 1; off < 1024; off <<= 1) {
    int v = src[t];
    if (t >= off) v += src[t - off];
    dst[t] = v;
    __syncthreads();
    int* tmp = src; src = dst; dst = tmp;
  }
  int excl = (t == 0) ? 0 : src[t - 1];
  int r0 = excl, r1 = excl + c0, r2 = excl + c0 + c1, r3 = excl + c0 + c1 + c2;
  row_ptr[b] = r0; row_ptr[b + 1] = r1; row_ptr[b + 2] = r2; row_ptr[b + 3] = r3;
  cursor[b] = r0; cursor[b + 1] = r1; cursor[b + 2] = r2; cursor[b + 3] = r3;
  if (t == 1023) row_ptr[4096] = src[1023];
}

__global__ void k_scatter(const int* __restrict__ eidx, const float* __restrict__ ew,
                          const float* __restrict__ dinv, int* __restrict__ cursor,
                          int* __restrict__ csrc, float* __restrict__ cnorm) {
  int e = blockIdx.x * 256 + threadIdx.x;
  if (e < NE) {
    int s = eidx[e], d = eidx[NE + e];
    int slot = atomicAdd(&cursor[d], 1);
    csrc[slot] = s;
    cnorm[slot] = dinv[s] * ew[e] * dinv[d];
  }
}

// ---------------- evecs -> bf16 transposed [128][NV] ----------------
__global__ __launch_bounds__(256) void k_evecsT(const float* __restrict__ ev, u16* __restrict__ evT) {
  __shared__ float tile[32][33];
  int t = threadIdx.x;
  int v0 = blockIdx.x * 32, k0 = blockIdx.y * 32;
  int r = t >> 3, c4 = (t & 7) * 4;
  float4 x = *(const float4*)(ev + (size_t)(v0 + r) * 128 + k0 + c4);
  tile[r][c4] = x.x; tile[r][c4 + 1] = x.y; tile[r][c4 + 2] = x.z; tile[r][c4 + 3] = x.w;
  __syncthreads();
  u16* dst = evT + (size_t)(k0 + r) * NV + v0 + c4;
  dst[0] = f2bf(tile[c4][r]); dst[1] = f2bf(tile[c4 + 1][r]);
  dst[2] = f2bf(tile[c4 + 2][r]); dst[3] = f2bf(tile[c4 + 3][r]);
}

// ---------------- pipelined bf16 MFMA GEMM: C(MxN) = A(MxK) @ BT(NxK)^T -----
// BM=128, BK=64, KPAD=72. Register-prefetch: next tile's global loads are
// issued before the current tile's MFMA phase (T3 2-phase minimum pattern).
template<int BN, bool AF32, bool ATRANS>
__global__ __launch_bounds__(256) void gemm_k(
    const void* __restrict__ Aptr, const void* __restrict__ A2, int zsplit2,
    const u16* __restrict__ BT, float* __restrict__ Cpart,
    int M, int N, int lda, int ldbt, int kchunk) {
  constexpr int NF = BN / 32;
  constexpr int KP = 72;
  constexpr int NBJ = BN / 32;   // uint4 loads/thread for B tile (BN x 64)
  __shared__ u16 lA[128 * KP];
  __shared__ u16 lB[BN * KP];
  const int t = threadIdx.x;
  const int m0 = blockIdx.x * 128, n0 = blockIdx.y * BN;
  const void* Ause = Aptr;
  int kz = blockIdx.z;
  if (A2 != nullptr && kz >= zsplit2) { Ause = A2; kz -= zsplit2; }
  const int kbeg = kz * kchunk;
  const int kend = kbeg + kchunk;
  const int lane = t & 63, wave = t >> 6;
  const int wm = (wave >> 1) * 64, wn = (wave & 1) * (BN / 2);

  float4 raf[8];   // AF32 staging regs
  uint4  rab[4];   // bf16 A staging regs
  uint4  rb[NBJ];  // B staging regs

  auto LOAD = [&](int k0) {
    if constexpr (AF32) {
      #pragma unroll
      for (int j = 0; j < 8; j++) {
        int idx = j * 256 + t;
        int r = idx >> 4, c4 = (idx & 15) * 4;
        raf[j] = *(const float4*)((const float*)Ause + (size_t)(m0 + r) * lda + k0 + c4);
      }
    } else if constexpr (!ATRANS) {
      #pragma unroll
      for (int j = 0; j < 4; j++) {
        int idx = j * 256 + t;
        int r = idx >> 3, c8 = (idx & 7) * 8;
        rab[j] = *(const uint4*)((const u16*)Ause + (size_t)(m0 + r) * lda + k0 + c8);
      }
    } else {
      #pragma unroll
      for (int j = 0; j < 4; j++) {
        int srow = wave * 16 + j * 4 + (lane >> 4);
        int c16 = (lane & 15) * 8;
        rab[j] = *(const uint4*)((const u16*)Ause + (size_t)(k0 + srow) * lda + m0 + c16);
      }
    }
    #pragma unroll
    for (int j = 0; j < NBJ; j++) {
      int idx = j * 256 + t;
      int r = idx >> 3, c8 = (idx & 7) * 8;
      rb[j] = *(const uint4*)(BT + (size_t)(n0 + r) * ldbt + k0 + c8);
    }
  };

  auto STORE = [&]() {
    if constexpr (AF32) {
      #pragma unroll
      for (int j = 0; j < 8; j++) {
        int idx = j * 256 + t;
        int r = idx >> 4, c4 = (idx & 15) * 4;
        u16 w[4] = {f2bf(raf[j].x), f2bf(raf[j].y), f2bf(raf[j].z), f2bf(raf[j].w)};
        *(uint2*)&lA[r * KP + c4] = *(uint2*)w;
      }
    } else if constexpr (!ATRANS) {
      #pragma unroll
      for (int j = 0; j < 4; j++) {
        int idx = j * 256 + t;
        int r = idx >> 3, c8 = (idx & 7) * 8;
        *(uint4*)&lA[r * KP + c8] = rab[j];
      }
    } else {
      #pragma unroll
      for (int j = 0; j < 4; j++) {
        int srow = wave * 16 + j * 4 + (lane >> 4);
        int c16 = (lane & 15) * 8;
        const u16* vals = (const u16*)&rab[j];
        #pragma unroll
        for (int q = 0; q < 8; q++) lA[(c16 + q) * KP + srow] = vals[q];
      }
    }
    #pragma unroll
    for (int j = 0; j < NBJ; j++) {
      int idx = j * 256 + t;
      int r = idx >> 3, c8 = (idx & 7) * 8;
      *(uint4*)&lB[r * KP + c8] = rb[j];
    }
  };

  f32x4 acc[4][NF];
  #pragma unroll
  for (int a = 0; a < 4; a++)
    #pragma unroll
    for (int b = 0; b < NF; b++) acc[a][b] = f32x4{0.f, 0.f, 0.f, 0.f};

  LOAD(kbeg);
  STORE();
  __syncthreads();
  if (kbeg + 64 < kend) LOAD(kbeg + 64);

  for (int k0 = kbeg; ; k0 += 64) {
    #pragma unroll
    for (int kk = 0; kk < 2; kk++) {
      sh8 af[4], bfv[NF];
      #pragma unroll
      for (int mf = 0; mf < 4; mf++)
        af[mf] = *(const sh8*)&lA[(wm + mf * 16 + (lane & 15)) * KP + kk * 32 + (lane >> 4) * 8];
      #pragma unroll
      for (int nf = 0; nf < NF; nf++)
        bfv[nf] = *(const sh8*)&lB[(wn + nf * 16 + (lane & 15)) * KP + kk * 32 + (lane >> 4) * 8];
      #pragma unroll
      for (int mf = 0; mf < 4; mf++)
        #pragma unroll
        for (int nf = 0; nf < NF; nf++)
          acc[mf][nf] = __builtin_amdgcn_mfma_f32_16x16x32_bf16(af[mf], bfv[nf], acc[mf][nf], 0, 0, 0);
    }
    if (k0 + 64 >= kend) break;
    __syncthreads();
    STORE();                       // consumes prefetched regs (waits vmcnt by dep)
    __syncthreads();
    if (k0 + 128 < kend) LOAD(k0 + 128);
  }

  float* C = Cpart + (size_t)blockIdx.z * M * N;
  #pragma unroll
  for (int mf = 0; mf < 4; mf++)
    #pragma unroll
    for (int nf = 0; nf < NF; nf++) {
      const int row = m0 + wm + mf * 16 + (lane >> 4) * 4;
      const int col = n0 + wn + nf * 16 + (lane & 15);
      #pragma unroll
      for (int q = 0; q < 4; q++)
        C[(size_t)(row + q) * N + col] = acc[mf][nf][q];
    }
}

__global__ void k_reduce(const float* __restrict__ parts, float* __restrict__ dst, int len, int nz) {
  int i = (blockIdx.x * 256 + threadIdx.x) * 4;
  if (i >= len) return;
  float4 s = *(const float4*)(parts + i);
  for (int z = 1; z < nz; z++) {
    float4 v = *(const float4*)(parts + (size_t)z * len + i);
    s.x += v.x; s.y += v.y; s.z += v.z; s.w += v.w;
  }
  *(float4*)(dst + i) = s;
}

// two matrices packed: dst[mat*len + j] = sum_z parts[(mat*nz+z)*len + j]
__global__ void k_reduce2(const float* __restrict__ parts, float* __restrict__ dst, int len, int nz) {
  int i = (blockIdx.x * 256 + threadIdx.x) * 4;
  if (i >= 2 * len) return;
  int mat = i / len, j = i - mat * len;
  const float* src = parts + (size_t)mat * nz * len + j;
  float4 s = *(const float4*)src;
  for (int z = 1; z < nz; z++) {
    float4 v = *(const float4*)(src + (size_t)z * len);
    s.x += v.x; s.y += v.y; s.z += v.z; s.w += v.w;
  }
  *(float4*)(dst + i) = s;
}

// ---------------- fused lin1/lin2 (C_IN=128 -> DW=64) ----------------
__global__ __launch_bounds__(256) void k_lin_both(const float* __restrict__ x_in,
    const float* __restrict__ graph_x, const float* __restrict__ W1,
    const float* __restrict__ b1, const float* __restrict__ W2,
    const float* __restrict__ b2, float* __restrict__ outV, float* __restrict__ outG) {
  __shared__ float lW[8192];
  __shared__ float lb[64];
  int bb = blockIdx.x;
  bool isV = bb < 2048;
  const float* W = isV ? W1 : W2;
  const float* bi = isV ? b1 : b2;
  const float* A = isV ? x_in : graph_x;
  float* out = isV ? outV : outG;
  int rb = isV ? bb : bb - 2048;
  int t = threadIdx.x;
  for (int i = t; i < 8192; i += 256) lW[i] = W[i];
  if (t < 64) lb[t] = bi[t];
  __syncthreads();
  int row = rb * 4 + (t >> 6), c = t & 63;
  const float* Ar = A + (size_t)row * 128;
  float acc = lb[c];
  #pragma unroll 8
  for (int k = 0; k < 128; k++) acc += Ar[k] * lW[k * 64 + c];
  out[(size_t)row * 64 + c] = acc;
}

// ---------------- spectral: sliced partial sums, no atomics ----------------
__global__ __launch_bounds__(64) void k_spec_part(const float* __restrict__ evecs,
    const float* __restrict__ mass, const float* __restrict__ dx, float* __restrict__ sp) {
  int k = blockIdx.x, c = threadIdx.x;
  int v0 = blockIdx.y * 256;
  float a0 = 0, a1 = 0, a2 = 0, a3 = 0;
  for (int v = v0; v < v0 + 256; v += 4) {
    a0 += evecs[(size_t)(v + 0) * 128 + k] * mass[v + 0] * dx[(size_t)(v + 0) * 64 + c];
    a1 += evecs[(size_t)(v + 1) * 128 + k] * mass[v + 1] * dx[(size_t)(v + 1) * 64 + c];
    a2 += evecs[(size_t)(v + 2) * 128 + k] * mass[v + 2] * dx[(size_t)(v + 2) * 64 + c];
    a3 += evecs[(size_t)(v + 3) * 128 + k] * mass[v + 3] * dx[(size_t)(v + 3) * 64 + c];
  }
  sp[(size_t)blockIdx.y * 8192 + k * 64 + c] = (a0 + a1) + (a2 + a3);
}

// Es[k][c] = exp(-evals[k]*t[c]) * sum_z sp[z][k][c]
__global__ void k_es(const float* __restrict__ sp, const float* __restrict__ evals,
                     const float* __restrict__ dt, float* __restrict__ Es) {
  int i = blockIdx.x * 256 + threadIdx.x;
  int k = i >> 6, c = i & 63;
  float s = 0.f;
  #pragma unroll 8
  for (int z = 0; z < NSLICE; z++) s += sp[(size_t)z * 8192 + i];
  Es[i] = expf(-evals[k] * fmaxf(dt[c], 1e-8f)) * s;
}

// ---------------- fused xd + gradient features ----------------
__global__ __launch_bounds__(256) void k_xdgf(const float* __restrict__ evecs,
    const float* __restrict__ GXE, const float* __restrict__ GYE,
    const float* __restrict__ Es, const float* __restrict__ Are,
    const float* __restrict__ Aim, float* __restrict__ xd, float* __restrict__ gf) {
  __shared__ float lE[8192];
  __shared__ float lr[4096], li[4096];
  __shared__ float lgx[256], lgy[256];
  int t = threadIdx.x;
  for (int i = t; i < 8192; i += 256) lE[i] = Es[i];
  for (int i = t; i < 4096; i += 256) { lr[i] = Are[i]; li[i] = Aim[i]; }
  __syncthreads();
  int wr = t >> 6, c = t & 63;
  int row = blockIdx.x * 4 + wr;
  const float* er = evecs + (size_t)row * 128;
  const float* xr = GXE + (size_t)row * 128;
  const float* yr = GYE + (size_t)row * 128;
  float a0 = 0, a1 = 0, a2 = 0;
  #pragma unroll 8
  for (int k = 0; k < 128; k++) {
    float s = lE[k * 64 + c];
    a0 += er[k] * s; a1 += xr[k] * s; a2 += yr[k] * s;
  }
  lgx[wr * 64 + c] = a1;
  lgy[wr * 64 + c] = a2;
  __syncthreads();
  float br = 0.f, bi = 0.f;
  #pragma unroll 8
  for (int k = 0; k < 64; k++) {
    float gx = lgx[wr * 64 + k], gy = lgy[wr * 64 + k];
    float ar = lr[k * 64 + c], ai = li[k * 64 + c];
    br += gx * ar - gy * ai;
    bi += gy * ar + gx * ai;
  }
  xd[(size_t)row * 64 + c] = a0;
  gf[(size_t)row * 64 + c] = tanhf(a1 * br + a2 * bi);
}

__global__ __launch_bounds__(256) void k_mlp0(const float* __restrict__ dx,
    const float* __restrict__ xd, const float* __restrict__ gf,
    const float* __restrict__ W0, const float* __restrict__ b0, float* __restrict__ h1) {
  __shared__ float lW[12288];
  __shared__ float lb[64];
  int t = threadIdx.x;
  for (int i = t; i < 12288; i += 256) lW[i] = W0[i];
  if (t < 64) lb[t] = b0[t];
  __syncthreads();
  int row = blockIdx.x * 4 + (t >> 6), c = t & 63;
  const float* a0 = dx + (size_t)row * 64;
  const float* a1 = xd + (size_t)row * 64;
  const float* a2 = gf + (size_t)row * 64;
  float acc = lb[c];
  #pragma unroll 8
  for (int k = 0; k < 64; k++) acc += a0[k] * lW[k * 64 + c];
  #pragma unroll 8
  for (int k = 0; k < 64; k++) acc += a1[k] * lW[(64 + k) * 64 + c];
  #pragma unroll 8
  for (int k = 0; k < 64; k++) acc += a2[k] * lW[(128 + k) * 64 + c];
  h1[(size_t)row * 64 + c] = fmaxf(acc, 0.f);
}

// fused mlp1 + mlp2 + residual: dx += relu(h1@W1+b1)@W2 + b2
__global__ __launch_bounds__(256) void k_mlp12(const float* __restrict__ h1,
    const float* __restrict__ W1, const float* __restrict__ b1,
    const float* __restrict__ W2, const float* __restrict__ b2, float* __restrict__ dx) {
  __shared__ float l1[4096], l2[4096], lb1[64], lb2[64], lrow[256];
  int t = threadIdx.x;
  for (int i = t; i < 4096; i += 256) { l1[i] = W1[i]; l2[i] = W2[i]; }
  if (t < 64) lb1[t] = b1[t];
  else if (t < 128) lb2[t - 64] = b2[t - 64];
  __syncthreads();
  int wr = t >> 6, c = t & 63;
  int row = blockIdx.x * 4 + wr;
  const float* hr = h1 + (size_t)row * 64;
  float h2 = lb1[c];
  #pragma unroll 8
  for (int k = 0; k < 64; k++) h2 += hr[k] * l1[k * 64 + c];
  h2 = fmaxf(h2, 0.f);
  lrow[wr * 64 + c] = h2;
  __syncthreads();
  float o = lb2[c] + dx[(size_t)row * 64 + c];
  #pragma unroll 8
  for (int k = 0; k < 64; k++) o += lrow[wr * 64 + k] * l2[k * 64 + c];
  dx[(size_t)row * 64 + c] = o;
}

// ---------------- small fp32 matmul (64x64 weights) ----------------
template<bool BIAS, bool RELU, bool RES>
__global__ __launch_bounds__(256) void k_mm64(const float* __restrict__ A,
    const float* __restrict__ W, const float* __restrict__ b,
    const float* __restrict__ res, float* __restrict__ out) {
  __shared__ float lW[4096];
  __shared__ float lb[64];
  int t = threadIdx.x;
  for (int i = t; i < 4096; i += 256) lW[i] = W[i];
  if constexpr (BIAS) { if (t < 64) lb[t] = b[t]; }
  __syncthreads();
  int row = blockIdx.x * 4 + (t >> 6), c = t & 63;
  const float* Ar = A + (size_t)row * 64;
  float acc = 0.f;
  #pragma unroll 8
  for (int k = 0; k < 64; k++) acc += Ar[k] * lW[k * 64 + c];
  if constexpr (BIAS) acc += lb[c];
  if constexpr (RES) acc += res[(size_t)row * 64 + c];
  if constexpr (RELU) acc = fmaxf(acc, 0.f);
  out[(size_t)row * 64 + c] = acc;
}

template<bool TP, bool TQ>
__global__ __launch_bounds__(256) void k_mm_dual(const float* __restrict__ A,
    const float* __restrict__ W1, const float* __restrict__ W2,
    float* __restrict__ P, float* __restrict__ Q,
    u16* __restrict__ PT, u16* __restrict__ QT, int R) {
  __shared__ float l1[4096], l2[4096];
  int t = threadIdx.x;
  for (int i = t; i < 4096; i += 256) { l1[i] = W1[i]; l2[i] = W2[i]; }
  __syncthreads();
  int row = blockIdx.x * 4 + (t >> 6), c = t & 63;
  const float* Ar = A + (size_t)row * 64;
  float p = 0.f, q = 0.f;
  #pragma unroll 8
  for (int k = 0; k < 64; k++) { float a = Ar[k]; p += a * l1[k * 64 + c]; q += a * l2[k * 64 + c]; }
  P[(size_t)row * 64 + c] = p;
  Q[(size_t)row * 64 + c] = q;
  if constexpr (TP) PT[(size_t)c * R + row] = f2bf(p);
  if constexpr (TQ) QT[(size_t)c * R + row] = f2bf(q);
}

// ---------------- GCN agg + next matmul fused ----------------
__global__ __launch_bounds__(64) void k_aggmm(const float* __restrict__ xw,
    const int* __restrict__ rp, const int* __restrict__ csrc,
    const float* __restrict__ cnorm, const float* __restrict__ invdeg,
    const float* __restrict__ b1, const float* __restrict__ W2, float* __restrict__ out) {
  __shared__ float lrow[64];
  int g = blockIdx.x, c = threadIdx.x;
  float acc = xw[(size_t)g * 64 + c] * invdeg[g] + b1[c];
  int j1 = rp[g + 1];
  for (int j = rp[g]; j < j1; j++) acc += cnorm[j] * xw[(size_t)csrc[j] * 64 + c];
  acc = fmaxf(acc, 0.f);
  lrow[c] = acc;
  __syncthreads();
  float o = 0.f;
  #pragma unroll 8
  for (int k = 0; k < 64; k++) o += lrow[k] * W2[k * 64 + c];
  out[(size_t)g * 64 + c] = o;
}

__global__ __launch_bounds__(64) void k_aggdual(const float* __restrict__ xw,
    const int* __restrict__ rp, const int* __restrict__ csrc,
    const float* __restrict__ cnorm, const float* __restrict__ invdeg,
    const float* __restrict__ b2, const float* __restrict__ gsw,
    const float* __restrict__ sgw, float* __restrict__ xw_g,
    float* __restrict__ xw2_g, u16* __restrict__ xwgT) {
  __shared__ float lrow[64];
  int g = blockIdx.x, c = threadIdx.x;
  float acc = xw[(size_t)g * 64 + c] * invdeg[g] + b2[c];
  int j1 = rp[g + 1];
  for (int j = rp[g]; j < j1; j++) acc += cnorm[j] * xw[(size_t)csrc[j] * 64 + c];
  lrow[c] = acc;
  __syncthreads();
  float p = 0.f, q = 0.f;
  #pragma unroll 8
  for (int k = 0; k < 64; k++) {
    float r = lrow[k];
    p += r * gsw[k * 64 + c];
    q += r * sgw[k * 64 + c];
  }
  xw_g[(size_t)g * 64 + c] = p;
  xw2_g[(size_t)g * 64 + c] = q;
  xwgT[(size_t)c * NG + g] = f2bf(p);
}

// ---------------- fused bipartite combine ----------------
__global__ void k_combine(const float* __restrict__ xw_v, const float* __restrict__ Wbp,
    const float* __restrict__ xw2_v, const float* __restrict__ xw_g,
    const float* __restrict__ WbTp, const float* __restrict__ xw2_g,
    const float* __restrict__ inv_deg_v, const float* __restrict__ rsv,
    const float* __restrict__ inv_deg_g, const float* __restrict__ rsg,
    const float* __restrict__ gsb, const float* __restrict__ sgb,
    float* __restrict__ dx, float* __restrict__ gx) {
  int idx = blockIdx.x * 256 + threadIdx.x;
  if (idx < NV * 64) {
    int v = idx >> 6, c = idx & 63;
    dx[idx] = 0.5f * (xw_v[idx] * inv_deg_v[v] + Wbp[idx] * rsv[v] + gsb[c] + xw2_v[idx] + sgb[c]);
  } else {
    int j = idx - NV * 64;
    int g = j >> 6, c = j & 63;
    gx[j] = 0.5f * (xw_g[j] + gsb[c] + xw2_g[j] * inv_deg_g[g] + WbTp[j] * rsg[g] + sgb[c]);
  }
}

// =================================================================
extern "C" void kernel_launch(void* const* d_in, const int* in_sizes, int n_in,
                              void* d_out, int out_size, void* d_ws, size_t ws_size,
                              hipStream_t stream) {
  const float* vertices  = (const float*)d_in[0];
  const float* graph_pos = (const float*)d_in[1];
  const float* x_in      = (const float*)d_in[2];
  const float* graph_x   = (const float*)d_in[3];
  const float* mass      = (const float*)d_in[4];
  const float* evals     = (const float*)d_in[5];
  const float* evecs     = (const float*)d_in[6];
  const float* gradX     = (const float*)d_in[7];
  const float* gradY     = (const float*)d_in[8];
  const int*   eidx      = (const int*)d_in[9];
  const float* ew        = (const float*)d_in[10];
  const float* lin1_w    = (const float*)d_in[11];
  const float* lin1_b    = (const float*)d_in[12];
  const float* lin2_w    = (const float*)d_in[13];
  const float* lin2_b    = (const float*)d_in[14];
  const float* diff_time = (const float*)d_in[15];
  const float* A_re      = (const float*)d_in[16];
  const float* A_im      = (const float*)d_in[17];
  const float* mlp_w0    = (const float*)d_in[18];
  const float* mlp_b0    = (const float*)d_in[19];
  const float* mlp_w1    = (const float*)d_in[20];
  const float* mlp_b1    = (const float*)d_in[21];
  const float* mlp_w2    = (const float*)d_in[22];
  const float* mlp_b2    = (const float*)d_in[23];
  const float* gcn1_w    = (const float*)d_in[24];
  const float* gcn1_b    = (const float*)d_in[25];
  const float* gcn2_w    = (const float*)d_in[26];
  const float* gcn2_b    = (const float*)d_in[27];
  const float* gs_w      = (const float*)d_in[28];
  const float* gs_b      = (const float*)d_in[29];
  const float* sg_w      = (const float*)d_in[30];
  const float* sg_b      = (const float*)d_in[31];

  char* base = (char*)d_ws;
  size_t off = 0;
  auto alloc = [&](size_t nbytes) -> void* {
    void* p = base + off;
    off += (nbytes + 255) & ~(size_t)255;
    return p;
  };
  const size_t MBy = 1024 * 1024;
  u16*   Wb_bf   = (u16*)alloc((size_t)NV * NG * 2);        // 64 MB
  u16*   evecsT  = (u16*)alloc((size_t)128 * NV * 2);
  float* GXE2    = (float*)alloc((size_t)2 * NV * 128 * 4); // GXE | GYE contiguous
  float* GXE     = GXE2;
  float* GYE     = GXE2 + (size_t)NV * 128;
  float* sp      = (float*)alloc((size_t)NSLICE * 8192 * 4);
  float* Es      = (float*)alloc(8192 * 4);
  float* diffx   = (float*)alloc((size_t)NV * 64 * 4);
  float* gxb     = (float*)alloc((size_t)NG * 64 * 4);
  float* xd      = (float*)alloc((size_t)NV * 64 * 4);
  float* gf      = (float*)alloc((size_t)NV * 64 * 4);
  float* h1      = (float*)alloc((size_t)NV * 64 * 4);
  float* xw_v    = (float*)alloc((size_t)NV * 64 * 4);
  float* xw2_v   = (float*)alloc((size_t)NV * 64 * 4);
  float* xw_g    = (float*)alloc((size_t)NG * 64 * 4);
  float* xw2_g   = (float*)alloc((size_t)NG * 64 * 4);
  float* xw1     = (float*)alloc((size_t)NG * 64 * 4);
  float* xw2k    = (float*)alloc((size_t)NG * 64 * 4);
  u16*   xwgT    = (u16*)alloc((size_t)64 * NG * 2);
  u16*   xw2vT   = (u16*)alloc((size_t)64 * NV * 2);
  float* Wbp     = (float*)alloc((size_t)NV * 64 * 4);
  float* WbTp    = (float*)alloc((size_t)NG * 64 * 4);
  float* deg_v   = (float*)alloc(NV * 4);
  float* inv_deg_v = (float*)alloc(NV * 4);
  float* rsv     = (float*)alloc(NV * 4);
  float* deg_g   = (float*)alloc(NG * 4);
  float* inv_deg_g = (float*)alloc(NG * 4);
  float* rsg     = (float*)alloc(NG * 4);
  float* deg_e   = (float*)alloc(NG * 4);
  float* invdeg_e = (float*)alloc(NG * 4);
  float* dinv_e  = (float*)alloc(NG * 4);
  int*   cnt     = (int*)alloc(NG * 4);
  int*   row_ptr = (int*)alloc((NG + 1) * 4);
  int*   cursor  = (int*)alloc(NG * 4);
  int*   csr_src = (int*)alloc(NE * 4);
  float* csr_norm = (float*)alloc(NE * 4);

  // optional tiers: explicit WbT (64 MB) and larger parts for k-split
  size_t avail = ws_size > off ? ws_size - off : 0;
  u16* WbT_bf = nullptr;
  int nzHalf;
  size_t partsBytes;
  if (avail >= 129 * MBy)      { WbT_bf = (u16*)alloc((size_t)NG * NV * 2); partsBytes = 64 * MBy; nzHalf = 8; }
  else if (avail >= 97 * MBy)  { WbT_bf = (u16*)alloc((size_t)NG * NV * 2); partsBytes = 32 * MBy; nzHalf = 4; }
  else if (avail >= 81 * MBy)  { WbT_bf = (u16*)alloc((size_t)NG * NV * 2); partsBytes = 16 * MBy; nzHalf = 2; }
  else if (avail >= 33 * MBy)  { partsBytes = 32 * MBy; nzHalf = 4; }
  else                          { partsBytes = 16 * MBy; nzHalf = 2; }
  float* parts = (float*)alloc(partsBytes);
  if (off > ws_size) return;  // insufficient workspace -> fail loudly

  dim3 B256(256);

  // ---------- setup ----------
  k_fill4<<<dim3(80), B256, 0, stream>>>(deg_v, deg_g, deg_e, cnt);
  k_wb_build<<<dim3(128, 64), B256, 0, stream>>>(vertices, graph_pos, Wb_bf, WbT_bf, deg_v, deg_g);
  k_edge_prep<<<dim3(256), B256, 0, stream>>>(eidx, ew, deg_e, cnt);
  k_recips<<<dim3(64), B256, 0, stream>>>(deg_v, inv_deg_v, rsv, deg_g, inv_deg_g, rsg,
                                          deg_e, invdeg_e, dinv_e);
  k_scan<<<dim3(1), dim3(1024), 0, stream>>>(cnt, row_ptr, cursor);
  k_scatter<<<dim3(256), B256, 0, stream>>>(eidx, ew, dinv_e, cursor, csr_src, csr_norm);
  k_evecsT<<<dim3(256, 4), B256, 0, stream>>>(evecs, evecsT);
  // GXE = gradX @ evecs, GYE = gradY @ evecs (z-packed, k-split nzHalf each)
  gemm_k<128, true, false><<<dim3(64, 1, 2 * nzHalf), B256, 0, stream>>>(
      gradX, gradY, nzHalf, evecsT, parts, NV, 128, NV, NV, 8192 / nzHalf);
  k_reduce2<<<dim3(2048), B256, 0, stream>>>(parts, GXE2, NV * 128, nzHalf);
  k_lin_both<<<dim3(3072), B256, 0, stream>>>(x_in, graph_x, lin1_w, lin1_b, lin2_w, lin2_b, diffx, gxb);

  // ---------- 4 blocks ----------
  for (int i = 0; i < 4; i++) {
    const float* dtrow = diff_time + i * 64;
    k_spec_part<<<dim3(128, NSLICE), dim3(64), 0, stream>>>(evecs, mass, diffx, sp);
    k_es<<<dim3(32), B256, 0, stream>>>(sp, evals, dtrow, Es);
    k_xdgf<<<dim3(2048), B256, 0, stream>>>(evecs, GXE, GYE, Es, A_re + i * 4096, A_im + i * 4096, xd, gf);
    k_mlp0<<<dim3(2048), B256, 0, stream>>>(diffx, xd, gf, mlp_w0 + i * 12288, mlp_b0 + i * 64, h1);
    k_mlp12<<<dim3(2048), B256, 0, stream>>>(h1, mlp_w1 + i * 4096, mlp_b1 + i * 64,
        mlp_w2 + i * 4096, mlp_b2 + i * 64, diffx);
    // graph GCN (2 convs) + graph-side dual projection
    k_mm64<false, false, false><<<dim3(1024), B256, 0, stream>>>(gxb, gcn1_w + i * 4096, nullptr, nullptr, xw1);
    k_aggmm<<<dim3(NG), dim3(64), 0, stream>>>(xw1, row_ptr, csr_src, csr_norm, invdeg_e,
        gcn1_b + i * 64, gcn2_w + i * 4096, xw2k);
    k_aggdual<<<dim3(NG), dim3(64), 0, stream>>>(xw2k, row_ptr, csr_src, csr_norm, invdeg_e,
        gcn2_b + i * 64, gs_w + i * 4096, sg_w + i * 4096, xw_g, xw2_g, xwgT);
    // vertex-side dual projection
    k_mm_dual<false, true><<<dim3(2048), B256, 0, stream>>>(diffx, gs_w + i * 4096, sg_w + i * 4096,
        xw_v, xw2_v, nullptr, xw2vT, NV);
    // Wbp = Wb @ xw_g  (M=NV, K=NG, ksplit 8)
    gemm_k<64, false, false><<<dim3(64, 1, 8), B256, 0, stream>>>(
        Wb_bf, nullptr, 1 << 30, xwgT, parts, NV, 64, NG, NG, 512);
    k_reduce<<<dim3(512), B256, 0, stream>>>(parts, Wbp, NV * 64, 8);
    // WbTp = Wb^T @ xw2_v (M=NG, K=NV, ksplit 16)
    if (WbT_bf != nullptr) {
      gemm_k<64, false, false><<<dim3(32, 1, 16), B256, 0, stream>>>(
          WbT_bf, nullptr, 1 << 30, xw2vT, parts, NG, 64, NV, NV, 512);
    } else {
      gemm_k<64, false, true><<<dim3(32, 1, 16), B256, 0, stream>>>(
          Wb_bf, nullptr, 1 << 30, xw2vT, parts, NG, 64, NG, NV, 512);
    }
    k_reduce<<<dim3(256), B256, 0, stream>>>(parts, WbTp, NG * 64, 16);
    // fused combine
    k_combine<<<dim3(3072), B256, 0, stream>>>(xw_v, Wbp, xw2_v, xw_g, WbTp, xw2_g,
        inv_deg_v, rsv, inv_deg_g, rsg, gs_b + i * 64, sg_b + i * 64, diffx, gxb);
  }

  hipMemcpyAsync(d_out, diffx, (size_t)NV * 64 * 4, hipMemcpyDeviceToDevice, stream);
}

// Round 4
// 1169.820 us; speedup vs baseline: 1.1597x; 1.1597x over previous
//
#include <hip/hip_runtime.h>
#include <hip/hip_bf16.h>

typedef unsigned short u16;
typedef __attribute__((ext_vector_type(8))) short sh8;     // 8 x bf16 (4 VGPRs)
typedef __attribute__((ext_vector_type(4))) float f32x4;   // MFMA accum

#define NV 8192
#define NG 4096
#define NE 65536
#define NSLICE 32

__device__ __forceinline__ u16 f2bf(float f) {
  __hip_bfloat16 h = __float2bfloat16(f);
  return __builtin_bit_cast(u16, h);
}

// async global->LDS, 16B per lane; LDS dest = wave-uniform base + lane*16
__device__ __forceinline__ void gl_lds16(const void* g, void* l) {
  __builtin_amdgcn_global_load_lds(
      (const __attribute__((address_space(1))) void*)g,
      (__attribute__((address_space(3))) void*)l, 16, 0, 0);
}

// ---------------- setup fills ----------------
__global__ void k_fill4(float* __restrict__ deg_v, float* __restrict__ deg_g,
                        float* __restrict__ deg_e, int* __restrict__ cnt) {
  int i = blockIdx.x * 256 + threadIdx.x;
  if (i < NV) deg_v[i] = 1.f;
  int j = i - NV;
  if (j >= 0 && j < NG) deg_g[j] = 1.f;
  j -= NG;
  if (j >= 0 && j < NG) deg_e[j] = 1.f;
  j -= NG;
  if (j >= 0 && j < NG) cnt[j] = 0;
}

// ---------------- Wb build: W = (d<8)?exp(-d/4):0, row/col sums, optional WbT
__global__ __launch_bounds__(256) void k_wb_build(
    const float* __restrict__ vert, const float* __restrict__ gpos,
    u16* __restrict__ Wb, u16* __restrict__ WbT,
    float* __restrict__ deg_v, float* __restrict__ deg_g) {
  __shared__ float lv[192], lg[192], colp[256];
  __shared__ float tile[64][65];
  int t = threadIdx.x;
  int v0 = blockIdx.x * 64, g0 = blockIdx.y * 64;
  if (t < 192) { lv[t] = vert[(size_t)v0 * 3 + t]; lg[t] = gpos[(size_t)g0 * 3 + t]; }
  __syncthreads();
  int w = t >> 6, lane = t & 63;
  float gx_ = lg[lane * 3], gy_ = lg[lane * 3 + 1], gz_ = lg[lane * 3 + 2];
  float csum = 0.f;
  #pragma unroll 4
  for (int s = 0; s < 16; s++) {
    int vl = w + 4 * s;
    float dx = lv[vl * 3] - gx_, dy = lv[vl * 3 + 1] - gy_, dz = lv[vl * 3 + 2] - gz_;
    float d = sqrtf(dx * dx + dy * dy + dz * dz);
    float W = (d < 8.0f) ? expf(d * -0.25f) : 0.f;
    Wb[(size_t)(v0 + vl) * NG + g0 + lane] = f2bf(W);
    tile[vl][lane] = W;
    csum += W;
  }
  colp[t] = csum;
  __syncthreads();
  // row sums: 4 threads per row
  int r = t >> 2, q = t & 3;
  float rs = 0.f;
  #pragma unroll
  for (int j = 0; j < 16; j++) rs += tile[r][q * 16 + j];
  rs += __shfl_xor(rs, 1);
  rs += __shfl_xor(rs, 2);
  if (q == 0) atomicAdd(&deg_v[v0 + r], rs);
  if (w == 0) {
    float tot = colp[lane] + colp[64 + lane] + colp[128 + lane] + colp[192 + lane];
    atomicAdd(&deg_g[g0 + lane], tot);
  }
  if (WbT != nullptr) {
    #pragma unroll
    for (int j = 0; j < 2; j++) {
      int idx = j * 256 + t;
      int g = idx >> 3, v8 = (idx & 7) * 8;
      u16 pk[8];
      #pragma unroll
      for (int qq = 0; qq < 8; qq++) pk[qq] = f2bf(tile[v8 + qq][g]);
      *(uint4*)&WbT[(size_t)(g0 + g) * NV + v0 + v8] = *(uint4*)pk;
    }
  }
}

// all three recips in one launch
__global__ void k_recips(const float* __restrict__ deg_v, float* __restrict__ inv_v,
                         float* __restrict__ rs_v, const float* __restrict__ deg_g,
                         float* __restrict__ inv_g, float* __restrict__ rs_g,
                         const float* __restrict__ deg_e, float* __restrict__ inv_e,
                         float* __restrict__ rs_e) {
  int i = blockIdx.x * 256 + threadIdx.x;
  if (i < NV) { float d = deg_v[i]; inv_v[i] = 1.f / d; rs_v[i] = 1.f / sqrtf(d); }
  else if (i < NV + NG) {
    int j = i - NV; float d = deg_g[j]; inv_g[j] = 1.f / d; rs_g[j] = 1.f / sqrtf(d);
  } else if (i < NV + 2 * NG) {
    int j = i - NV - NG; float d = deg_e[j]; inv_e[j] = 1.f / d; rs_e[j] = 1.f / sqrtf(d);
  }
}

// ---------------- edge preprocessing (CSR) ----------------
__global__ void k_edge_prep(const int* __restrict__ eidx, const float* __restrict__ ew,
                            float* __restrict__ deg_e, int* __restrict__ cnt) {
  int e = blockIdx.x * 256 + threadIdx.x;
  if (e < NE) { int d = eidx[NE + e]; atomicAdd(&deg_e[d], ew[e]); atomicAdd(&cnt[d], 1); }
}

__global__ __launch_bounds__(1024) void k_scan(const int* __restrict__ cnt,
    int* __restrict__ row_ptr, int* __restrict__ cursor) {
  __shared__ int buf0[1024], buf1[1024];
  int t = threadIdx.x;
  int b = t * 4;
  int c0 = cnt[b], c1 = cnt[b + 1], c2 = cnt[b + 2], c3 = cnt[b + 3];
  int s = c0 + c1 + c2 + c3;
  buf0[t] = s;
  __syncthreads();
  int* src = buf0; int* dst = buf1;
  for (int off = 1; off < 1024; off <<= 1) {
    int v = src[t];
    if (t >= off) v += src[t - off];
    dst[t] = v;
    __syncthreads();
    int* tmp = src; src = dst; dst = tmp;
  }
  int excl = (t == 0) ? 0 : src[t - 1];
  int r0 = excl, r1 = excl + c0, r2 = excl + c0 + c1, r3 = excl + c0 + c1 + c2;
  row_ptr[b] = r0; row_ptr[b + 1] = r1; row_ptr[b + 2] = r2; row_ptr[b + 3] = r3;
  cursor[b] = r0; cursor[b + 1] = r1; cursor[b + 2] = r2; cursor[b + 3] = r3;
  if (t == 1023) row_ptr[4096] = src[1023];
}

__global__ void k_scatter(const int* __restrict__ eidx, const float* __restrict__ ew,
                          const float* __restrict__ dinv, int* __restrict__ cursor,
                          int* __restrict__ csrc, float* __restrict__ cnorm) {
  int e = blockIdx.x * 256 + threadIdx.x;
  if (e < NE) {
    int s = eidx[e], d = eidx[NE + e];
    int slot = atomicAdd(&cursor[d], 1);
    csrc[slot] = s;
    cnorm[slot] = dinv[s] * ew[e] * dinv[d];
  }
}

// ---------------- evecs -> bf16 transposed [128][NV] ----------------
__global__ __launch_bounds__(256) void k_evecsT(const float* __restrict__ ev, u16* __restrict__ evT) {
  __shared__ float tile[32][33];
  int t = threadIdx.x;
  int v0 = blockIdx.x * 32, k0 = blockIdx.y * 32;
  int r = t >> 3, c4 = (t & 7) * 4;
  float4 x = *(const float4*)(ev + (size_t)(v0 + r) * 128 + k0 + c4);
  tile[r][c4] = x.x; tile[r][c4 + 1] = x.y; tile[r][c4 + 2] = x.z; tile[r][c4 + 3] = x.w;
  __syncthreads();
  u16* dst = evT + (size_t)(k0 + r) * NV + v0 + c4;
  dst[0] = f2bf(tile[c4][r]); dst[1] = f2bf(tile[c4 + 1][r]);
  dst[2] = f2bf(tile[c4 + 2][r]); dst[3] = f2bf(tile[c4 + 3][r]);
}

// =============== setup GEMM: [GXE|GYE] = [gradX|gradY](fp32) @ evecsT^T =====
// BM=128, BN=128, BK=32. A staged to LDS as fp32 via global_load_lds with
// XOR-swizzled source (16B slot s holds global slot s^(r&7)); converted to
// bf16 after ds_read. Double-buffered, 2-phase (T3 minimum).
__global__ __launch_bounds__(256) void gemm_setup(
    const float* __restrict__ gXm, const float* __restrict__ gYm,
    const u16* __restrict__ evT, float* __restrict__ parts,
    int nzHalf, int kchunk) {
  __shared__ __align__(16) char smem[49152];   // 2 x (A 16KB fp32 + B 8KB bf16)
  const int t = threadIdx.x;
  const int lane = t & 63, wave = t >> 6;
  const int m0 = blockIdx.x * 128;
  int kz = blockIdx.z;
  const float* A = gXm;
  if (kz >= nzHalf) { A = gYm; kz -= nzHalf; }
  const int kbeg = kz * kchunk;
  const int nt = kchunk >> 5;
  const int wm = (wave >> 1) * 64, wn = (wave & 1) * 64;
  const int arl = lane >> 3, asl = lane & 7;   // A: 8 rows/instr, 8x16B slots/row
  const int brl = lane >> 2, bsl = lane & 3;   // B: 16 rows/instr, 4x16B slots/row

  f32x4 acc[4][4];
  #pragma unroll
  for (int a = 0; a < 4; a++)
    #pragma unroll
    for (int b = 0; b < 4; b++) acc[a][b] = f32x4{0.f, 0.f, 0.f, 0.f};

  auto STAGE = [&](int buf, int k0) {
    char* base = smem + buf * 24576;
    #pragma unroll
    for (int j = 0; j < 4; j++) {
      int R0 = (wave * 4 + j) * 8;
      int r = R0 + arl;
      int gs = asl ^ (r & 7);
      gl_lds16(A + (size_t)(m0 + r) * NV + k0 + gs * 4, base + R0 * 128);
    }
    char* bb = base + 16384;
    #pragma unroll
    for (int j = 0; j < 2; j++) {
      int R0 = (wave * 2 + j) * 16;
      int r = R0 + brl;
      int gs = bsl ^ (r & 3);
      gl_lds16(evT + (size_t)r * NV + k0 + gs * 8, bb + R0 * 64);
    }
  };

  auto COMPUTE = [&](int buf) {
    char* base = smem + buf * 24576;
    const float* Af = (const float*)base;
    const u16* Bf = (const u16*)(base + 16384);
    sh8 av[4], bv[4];
    #pragma unroll
    for (int mf = 0; mf < 4; mf++) {
      int r = wm + mf * 16 + (lane & 15);
      int b2 = (lane >> 4) * 2;
      float4 f0 = *(const float4*)(Af + r * 32 + ((b2) ^ (r & 7)) * 4);
      float4 f1 = *(const float4*)(Af + r * 32 + ((b2 + 1) ^ (r & 7)) * 4);
      sh8 v;
      v[0] = (short)f2bf(f0.x); v[1] = (short)f2bf(f0.y);
      v[2] = (short)f2bf(f0.z); v[3] = (short)f2bf(f0.w);
      v[4] = (short)f2bf(f1.x); v[5] = (short)f2bf(f1.y);
      v[6] = (short)f2bf(f1.z); v[7] = (short)f2bf(f1.w);
      av[mf] = v;
    }
    #pragma unroll
    for (int nf = 0; nf < 4; nf++) {
      int r = wn + nf * 16 + (lane & 15);
      int s = (lane >> 4) ^ (r & 3);
      bv[nf] = *(const sh8*)(Bf + r * 32 + s * 8);
    }
    #pragma unroll
    for (int mf = 0; mf < 4; mf++)
      #pragma unroll
      for (int nf = 0; nf < 4; nf++)
        acc[mf][nf] = __builtin_amdgcn_mfma_f32_16x16x32_bf16(av[mf], bv[nf], acc[mf][nf], 0, 0, 0);
  };

  STAGE(0, kbeg);
  __syncthreads();
  for (int ti = 0; ti < nt; ti++) {
    if (ti + 1 < nt) STAGE((ti + 1) & 1, kbeg + (ti + 1) * 32);
    COMPUTE(ti & 1);
    __syncthreads();
  }

  float* C = parts + (size_t)blockIdx.z * (NV * 128);
  #pragma unroll
  for (int mf = 0; mf < 4; mf++)
    #pragma unroll
    for (int nf = 0; nf < 4; nf++) {
      int row = m0 + wm + mf * 16 + (lane >> 4) * 4;
      int col = wn + nf * 16 + (lane & 15);
      #pragma unroll
      for (int q = 0; q < 4; q++)
        C[(size_t)(row + q) * 128 + col] = acc[mf][nf][q];
    }
}

// =============== bf16 GEMM (Wb / WbT products): C = A @ BT^T, N=64 ==========
// BM=128, BN=64, BK=64; global_load_lds + XOR swizzle; double-buffered 2-phase.
__global__ __launch_bounds__(256) void gemm_bf16(
    const u16* __restrict__ Ab, int lda, const u16* __restrict__ BT, int ldbt,
    float* __restrict__ parts, int M, int kchunk) {
  __shared__ __align__(16) char smem[49152];   // 2 x (A 16KB + B 8KB)
  const int t = threadIdx.x;
  const int lane = t & 63, wave = t >> 6;
  const int m0 = blockIdx.x * 128;
  const int kbeg = blockIdx.z * kchunk;
  const int nt = kchunk >> 6;
  const int wm = (wave >> 1) * 64, wn = (wave & 1) * 32;
  const int arl = lane >> 3, asl = lane & 7;

  f32x4 acc[4][2];
  #pragma unroll
  for (int a = 0; a < 4; a++)
    #pragma unroll
    for (int b = 0; b < 2; b++) acc[a][b] = f32x4{0.f, 0.f, 0.f, 0.f};

  auto STAGE = [&](int buf, int k0) {
    char* base = smem + buf * 24576;
    #pragma unroll
    for (int j = 0; j < 4; j++) {
      int R0 = (wave * 4 + j) * 8;
      int r = R0 + arl;
      int gs = asl ^ (r & 7);
      gl_lds16(Ab + (size_t)(m0 + r) * lda + k0 + gs * 8, base + R0 * 128);
    }
    char* bb = base + 16384;
    #pragma unroll
    for (int j = 0; j < 2; j++) {
      int R0 = (wave * 2 + j) * 8;
      int r = R0 + arl;
      int gs = asl ^ (r & 7);
      gl_lds16(BT + (size_t)r * ldbt + k0 + gs * 8, bb + R0 * 128);
    }
  };

  auto COMPUTE = [&](int buf) {
    char* base = smem + buf * 24576;
    const u16* Af = (const u16*)base;
    const u16* Bf = (const u16*)(base + 16384);
    #pragma unroll
    for (int kk = 0; kk < 2; kk++) {
      sh8 av[4], bv[2];
      #pragma unroll
      for (int mf = 0; mf < 4; mf++) {
        int r = wm + mf * 16 + (lane & 15);
        int g = kk * 4 + (lane >> 4);
        av[mf] = *(const sh8*)(Af + r * 64 + (g ^ (r & 7)) * 8);
      }
      #pragma unroll
      for (int nf = 0; nf < 2; nf++) {
        int r = wn + nf * 16 + (lane & 15);
        int g = kk * 4 + (lane >> 4);
        bv[nf] = *(const sh8*)(Bf + r * 64 + (g ^ (r & 7)) * 8);
      }
      #pragma unroll
      for (int mf = 0; mf < 4; mf++)
        #pragma unroll
        for (int nf = 0; nf < 2; nf++)
          acc[mf][nf] = __builtin_amdgcn_mfma_f32_16x16x32_bf16(av[mf], bv[nf], acc[mf][nf], 0, 0, 0);
    }
  };

  STAGE(0, kbeg);
  __syncthreads();
  for (int ti = 0; ti < nt; ti++) {
    if (ti + 1 < nt) STAGE((ti + 1) & 1, kbeg + (ti + 1) * 64);
    COMPUTE(ti & 1);
    __syncthreads();
  }

  float* C = parts + (size_t)blockIdx.z * M * 64;
  #pragma unroll
  for (int mf = 0; mf < 4; mf++)
    #pragma unroll
    for (int nf = 0; nf < 2; nf++) {
      int row = m0 + wm + mf * 16 + (lane >> 4) * 4;
      int col = wn + nf * 16 + (lane & 15);
      #pragma unroll
      for (int q = 0; q < 4; q++)
        C[(size_t)(row + q) * 64 + col] = acc[mf][nf][q];
    }
}

// ---------------- round-2 GEMM kept ONLY as low-ws ATRANS fallback ----------
template<int BN, bool AF32, bool ATRANS>
__global__ __launch_bounds__(256) void gemm_k(
    const void* __restrict__ Aptr, const void* __restrict__ A2, int zsplit2,
    const u16* __restrict__ BT, float* __restrict__ Cpart,
    int M, int N, int lda, int ldbt, int kchunk) {
  constexpr int NF = BN / 32;
  __shared__ u16 lA[128 * 40];
  __shared__ u16 lB[BN * 40];
  const int t = threadIdx.x;
  const int m0 = blockIdx.x * 128, n0 = blockIdx.y * BN;
  const void* Ause = Aptr;
  int kz = blockIdx.z;
  if (A2 != nullptr && kz >= zsplit2) { Ause = A2; kz -= zsplit2; }
  const int kbeg = kz * kchunk;
  const int lane = t & 63, wave = t >> 6;
  const int wm = (wave >> 1) * 64, wn = (wave & 1) * (BN / 2);
  f32x4 zero = {0.f, 0.f, 0.f, 0.f};
  f32x4 acc[4][NF];
  #pragma unroll
  for (int a = 0; a < 4; a++)
    #pragma unroll
    for (int b = 0; b < NF; b++) acc[a][b] = zero;

  for (int k0 = kbeg; k0 < kbeg + kchunk; k0 += 32) {
    if constexpr (!ATRANS) {
      const int r = t >> 1, cc = (t & 1) * 16;
      const u16* A = (const u16*)Ause + (size_t)(m0 + r) * lda + k0 + cc;
      *(uint4*)&lA[r * 40 + cc] = *(const uint4*)A;
      *(uint4*)&lA[r * 40 + cc + 8] = *(const uint4*)(A + 8);
    } else {
      const int kl = t >> 3, mb = (t & 7) * 16;
      const u16* A = (const u16*)Ause + (size_t)(k0 + kl) * lda + m0 + mb;
      u16 vals[16];
      *(uint4*)&vals[0] = *(const uint4*)A;
      *(uint4*)&vals[8] = *(const uint4*)(A + 8);
      #pragma unroll
      for (int j = 0; j < 16; j++) lA[(mb + j) * 40 + kl] = vals[j];
    }
    if constexpr (BN == 64) {
      const int r = t >> 2, cc = (t & 3) * 8;
      const u16* B = BT + (size_t)(n0 + r) * ldbt + k0 + cc;
      *(uint4*)&lB[r * 40 + cc] = *(const uint4*)B;
    } else {
      const int r = t >> 1, cc = (t & 1) * 16;
      const u16* B = BT + (size_t)(n0 + r) * ldbt + k0 + cc;
      *(uint4*)&lB[r * 40 + cc] = *(const uint4*)B;
      *(uint4*)&lB[r * 40 + cc + 8] = *(const uint4*)(B + 8);
    }
    __syncthreads();
    sh8 af[4], bfv[NF];
    #pragma unroll
    for (int mf = 0; mf < 4; mf++)
      af[mf] = *(const sh8*)&lA[(wm + mf * 16 + (lane & 15)) * 40 + (lane >> 4) * 8];
    #pragma unroll
    for (int nf = 0; nf < NF; nf++)
      bfv[nf] = *(const sh8*)&lB[(wn + nf * 16 + (lane & 15)) * 40 + (lane >> 4) * 8];
    #pragma unroll
    for (int mf = 0; mf < 4; mf++)
      #pragma unroll
      for (int nf = 0; nf < NF; nf++)
        acc[mf][nf] = __builtin_amdgcn_mfma_f32_16x16x32_bf16(af[mf], bfv[nf], acc[mf][nf], 0, 0, 0);
    __syncthreads();
  }
  float* C = Cpart + (size_t)blockIdx.z * M * N;
  #pragma unroll
  for (int mf = 0; mf < 4; mf++)
    #pragma unroll
    for (int nf = 0; nf < NF; nf++) {
      const int row = m0 + wm + mf * 16 + (lane >> 4) * 4;
      const int col = n0 + wn + nf * 16 + (lane & 15);
      #pragma unroll
      for (int q = 0; q < 4; q++)
        C[(size_t)(row + q) * N + col] = acc[mf][nf][q];
    }
}

__global__ void k_reduce(const float* __restrict__ parts, float* __restrict__ dst, int len, int nz) {
  int i = (blockIdx.x * 256 + threadIdx.x) * 4;
  if (i >= len) return;
  float4 s = *(const float4*)(parts + i);
  for (int z = 1; z < nz; z++) {
    float4 v = *(const float4*)(parts + (size_t)z * len + i);
    s.x += v.x; s.y += v.y; s.z += v.z; s.w += v.w;
  }
  *(float4*)(dst + i) = s;
}

// two matrices packed: dst[mat*len + j] = sum_z parts[(mat*nz+z)*len + j]
__global__ void k_reduce2(const float* __restrict__ parts, float* __restrict__ dst, int len, int nz) {
  int i = (blockIdx.x * 256 + threadIdx.x) * 4;
  if (i >= 2 * len) return;
  int mat = i / len, j = i - mat * len;
  const float* src = parts + (size_t)mat * nz * len + j;
  float4 s = *(const float4*)src;
  for (int z = 1; z < nz; z++) {
    float4 v = *(const float4*)(src + (size_t)z * len);
    s.x += v.x; s.y += v.y; s.z += v.z; s.w += v.w;
  }
  *(float4*)(dst + i) = s;
}

// ---------------- fused lin1/lin2 (C_IN=128 -> DW=64) ----------------
__global__ __launch_bounds__(256) void k_lin_both(const float* __restrict__ x_in,
    const float* __restrict__ graph_x, const float* __restrict__ W1,
    const float* __restrict__ b1, const float* __restrict__ W2,
    const float* __restrict__ b2, float* __restrict__ outV, float* __restrict__ outG) {
  __shared__ float lW[8192];
  __shared__ float lb[64];
  int bb = blockIdx.x;
  bool isV = bb < 2048;
  const float* W = isV ? W1 : W2;
  const float* bi = isV ? b1 : b2;
  const float* A = isV ? x_in : graph_x;
  float* out = isV ? outV : outG;
  int rb = isV ? bb : bb - 2048;
  int t = threadIdx.x;
  for (int i = t; i < 8192; i += 256) lW[i] = W[i];
  if (t < 64) lb[t] = bi[t];
  __syncthreads();
  int row = rb * 4 + (t >> 6), c = t & 63;
  const float* Ar = A + (size_t)row * 128;
  float acc = lb[c];
  #pragma unroll 8
  for (int k = 0; k < 128; k++) acc += Ar[k] * lW[k * 64 + c];
  out[(size_t)row * 64 + c] = acc;
}

// ---------------- spectral: sliced partial sums, no atomics ----------------
__global__ __launch_bounds__(64) void k_spec_part(const float* __restrict__ evecs,
    const float* __restrict__ mass, const float* __restrict__ dx, float* __restrict__ sp) {
  int k = blockIdx.x, c = threadIdx.x;
  int v0 = blockIdx.y * 256;
  float a0 = 0, a1 = 0, a2 = 0, a3 = 0;
  for (int v = v0; v < v0 + 256; v += 4) {
    a0 += evecs[(size_t)(v + 0) * 128 + k] * mass[v + 0] * dx[(size_t)(v + 0) * 64 + c];
    a1 += evecs[(size_t)(v + 1) * 128 + k] * mass[v + 1] * dx[(size_t)(v + 1) * 64 + c];
    a2 += evecs[(size_t)(v + 2) * 128 + k] * mass[v + 2] * dx[(size_t)(v + 2) * 64 + c];
    a3 += evecs[(size_t)(v + 3) * 128 + k] * mass[v + 3] * dx[(size_t)(v + 3) * 64 + c];
  }
  sp[(size_t)blockIdx.y * 8192 + k * 64 + c] = (a0 + a1) + (a2 + a3);
}

// Es[k][c] = exp(-evals[k]*t[c]) * sum_z sp[z][k][c]
__global__ void k_es(const float* __restrict__ sp, const float* __restrict__ evals,
                     const float* __restrict__ dt, float* __restrict__ Es) {
  int i = blockIdx.x * 256 + threadIdx.x;
  int k = i >> 6, c = i & 63;
  float s = 0.f;
  #pragma unroll 8
  for (int z = 0; z < NSLICE; z++) s += sp[(size_t)z * 8192 + i];
  Es[i] = expf(-evals[k] * fmaxf(dt[c], 1e-8f)) * s;
}

// ---------------- fused xd + gradient features ----------------
__global__ __launch_bounds__(256) void k_xdgf(const float* __restrict__ evecs,
    const float* __restrict__ GXE, const float* __restrict__ GYE,
    const float* __restrict__ Es, const float* __restrict__ Are,
    const float* __restrict__ Aim, float* __restrict__ xd, float* __restrict__ gf) {
  __shared__ float lE[8192];
  __shared__ float lr[4096], li[4096];
  __shared__ float lgx[256], lgy[256];
  int t = threadIdx.x;
  for (int i = t; i < 8192; i += 256) lE[i] = Es[i];
  for (int i = t; i < 4096; i += 256) { lr[i] = Are[i]; li[i] = Aim[i]; }
  __syncthreads();
  int wr = t >> 6, c = t & 63;
  int row = blockIdx.x * 4 + wr;
  const float* er = evecs + (size_t)row * 128;
  const float* xr = GXE + (size_t)row * 128;
  const float* yr = GYE + (size_t)row * 128;
  float a0 = 0, a1 = 0, a2 = 0;
  #pragma unroll 8
  for (int k = 0; k < 128; k++) {
    float s = lE[k * 64 + c];
    a0 += er[k] * s; a1 += xr[k] * s; a2 += yr[k] * s;
  }
  lgx[wr * 64 + c] = a1;
  lgy[wr * 64 + c] = a2;
  __syncthreads();
  float br = 0.f, bi = 0.f;
  #pragma unroll 8
  for (int k = 0; k < 64; k++) {
    float gx = lgx[wr * 64 + k], gy = lgy[wr * 64 + k];
    float ar = lr[k * 64 + c], ai = li[k * 64 + c];
    br += gx * ar - gy * ai;
    bi += gy * ar + gx * ai;
  }
  xd[(size_t)row * 64 + c] = a0;
  gf[(size_t)row * 64 + c] = tanhf(a1 * br + a2 * bi);
}

__global__ __launch_bounds__(256) void k_mlp0(const float* __restrict__ dx,
    const float* __restrict__ xd, const float* __restrict__ gf,
    const float* __restrict__ W0, const float* __restrict__ b0, float* __restrict__ h1) {
  __shared__ float lW[12288];
  __shared__ float lb[64];
  int t = threadIdx.x;
  for (int i = t; i < 12288; i += 256) lW[i] = W0[i];
  if (t < 64) lb[t] = b0[t];
  __syncthreads();
  int row = blockIdx.x * 4 + (t >> 6), c = t & 63;
  const float* a0 = dx + (size_t)row * 64;
  const float* a1 = xd + (size_t)row * 64;
  const float* a2 = gf + (size_t)row * 64;
  float acc = lb[c];
  #pragma unroll 8
  for (int k = 0; k < 64; k++) acc += a0[k] * lW[k * 64 + c];
  #pragma unroll 8
  for (int k = 0; k < 64; k++) acc += a1[k] * lW[(64 + k) * 64 + c];
  #pragma unroll 8
  for (int k = 0; k < 64; k++) acc += a2[k] * lW[(128 + k) * 64 + c];
  h1[(size_t)row * 64 + c] = fmaxf(acc, 0.f);
}

// fused mlp1 + mlp2 + residual: dx += relu(h1@W1+b1)@W2 + b2
__global__ __launch_bounds__(256) void k_mlp12(const float* __restrict__ h1,
    const float* __restrict__ W1, const float* __restrict__ b1,
    const float* __restrict__ W2, const float* __restrict__ b2, float* __restrict__ dx) {
  __shared__ float l1[4096], l2[4096], lb1[64], lb2[64], lrow[256];
  int t = threadIdx.x;
  for (int i = t; i < 4096; i += 256) { l1[i] = W1[i]; l2[i] = W2[i]; }
  if (t < 64) lb1[t] = b1[t];
  else if (t < 128) lb2[t - 64] = b2[t - 64];
  __syncthreads();
  int wr = t >> 6, c = t & 63;
  int row = blockIdx.x * 4 + wr;
  const float* hr = h1 + (size_t)row * 64;
  float h2 = lb1[c];
  #pragma unroll 8
  for (int k = 0; k < 64; k++) h2 += hr[k] * l1[k * 64 + c];
  h2 = fmaxf(h2, 0.f);
  lrow[wr * 64 + c] = h2;
  __syncthreads();
  float o = lb2[c] + dx[(size_t)row * 64 + c];
  #pragma unroll 8
  for (int k = 0; k < 64; k++) o += lrow[wr * 64 + k] * l2[k * 64 + c];
  dx[(size_t)row * 64 + c] = o;
}

// ---------------- small fp32 matmul (64x64 weights) ----------------
template<bool BIAS, bool RELU, bool RES>
__global__ __launch_bounds__(256) void k_mm64(const float* __restrict__ A,
    const float* __restrict__ W, const float* __restrict__ b,
    const float* __restrict__ res, float* __restrict__ out) {
  __shared__ float lW[4096];
  __shared__ float lb[64];
  int t = threadIdx.x;
  for (int i = t; i < 4096; i += 256) lW[i] = W[i];
  if constexpr (BIAS) { if (t < 64) lb[t] = b[t]; }
  __syncthreads();
  int row = blockIdx.x * 4 + (t >> 6), c = t & 63;
  const float* Ar = A + (size_t)row * 64;
  float acc = 0.f;
  #pragma unroll 8
  for (int k = 0; k < 64; k++) acc += Ar[k] * lW[k * 64 + c];
  if constexpr (BIAS) acc += lb[c];
  if constexpr (RES) acc += res[(size_t)row * 64 + c];
  if constexpr (RELU) acc = fmaxf(acc, 0.f);
  out[(size_t)row * 64 + c] = acc;
}

template<bool TP, bool TQ>
__global__ __launch_bounds__(256) void k_mm_dual(const float* __restrict__ A,
    const float* __restrict__ W1, const float* __restrict__ W2,
    float* __restrict__ P, float* __restrict__ Q,
    u16* __restrict__ PT, u16* __restrict__ QT, int R) {
  __shared__ float l1[4096], l2[4096];
  int t = threadIdx.x;
  for (int i = t; i < 4096; i += 256) { l1[i] = W1[i]; l2[i] = W2[i]; }
  __syncthreads();
  int row = blockIdx.x * 4 + (t >> 6), c = t & 63;
  const float* Ar = A + (size_t)row * 64;
  float p = 0.f, q = 0.f;
  #pragma unroll 8
  for (int k = 0; k < 64; k++) { float a = Ar[k]; p += a * l1[k * 64 + c]; q += a * l2[k * 64 + c]; }
  P[(size_t)row * 64 + c] = p;
  Q[(size_t)row * 64 + c] = q;
  if constexpr (TP) PT[(size_t)c * R + row] = f2bf(p);
  if constexpr (TQ) QT[(size_t)c * R + row] = f2bf(q);
}

// ---------------- GCN agg + next matmul fused ----------------
__global__ __launch_bounds__(64) void k_aggmm(const float* __restrict__ xw,
    const int* __restrict__ rp, const int* __restrict__ csrc,
    const float* __restrict__ cnorm, const float* __restrict__ invdeg,
    const float* __restrict__ b1, const float* __restrict__ W2, float* __restrict__ out) {
  __shared__ float lrow[64];
  int g = blockIdx.x, c = threadIdx.x;
  float acc = xw[(size_t)g * 64 + c] * invdeg[g] + b1[c];
  int j1 = rp[g + 1];
  for (int j = rp[g]; j < j1; j++) acc += cnorm[j] * xw[(size_t)csrc[j] * 64 + c];
  acc = fmaxf(acc, 0.f);
  lrow[c] = acc;
  __syncthreads();
  float o = 0.f;
  #pragma unroll 8
  for (int k = 0; k < 64; k++) o += lrow[k] * W2[k * 64 + c];
  out[(size_t)g * 64 + c] = o;
}

__global__ __launch_bounds__(64) void k_aggdual(const float* __restrict__ xw,
    const int* __restrict__ rp, const int* __restrict__ csrc,
    const float* __restrict__ cnorm, const float* __restrict__ invdeg,
    const float* __restrict__ b2, const float* __restrict__ gsw,
    const float* __restrict__ sgw, float* __restrict__ xw_g,
    float* __restrict__ xw2_g, u16* __restrict__ xwgT) {
  __shared__ float lrow[64];
  int g = blockIdx.x, c = threadIdx.x;
  float acc = xw[(size_t)g * 64 + c] * invdeg[g] + b2[c];
  int j1 = rp[g + 1];
  for (int j = rp[g]; j < j1; j++) acc += cnorm[j] * xw[(size_t)csrc[j] * 64 + c];
  lrow[c] = acc;
  __syncthreads();
  float p = 0.f, q = 0.f;
  #pragma unroll 8
  for (int k = 0; k < 64; k++) {
    float r = lrow[k];
    p += r * gsw[k * 64 + c];
    q += r * sgw[k * 64 + c];
  }
  xw_g[(size_t)g * 64 + c] = p;
  xw2_g[(size_t)g * 64 + c] = q;
  xwgT[(size_t)c * NG + g] = f2bf(p);
}

// ---------------- fused bipartite combine ----------------
__global__ void k_combine(const float* __restrict__ xw_v, const float* __restrict__ Wbp,
    const float* __restrict__ xw2_v, const float* __restrict__ xw_g,
    const float* __restrict__ WbTp, const float* __restrict__ xw2_g,
    const float* __restrict__ inv_deg_v, const float* __restrict__ rsv,
    const float* __restrict__ inv_deg_g, const float* __restrict__ rsg,
    const float* __restrict__ gsb, const float* __restrict__ sgb,
    float* __restrict__ dx, float* __restrict__ gx) {
  int idx = blockIdx.x * 256 + threadIdx.x;
  if (idx < NV * 64) {
    int v = idx >> 6, c = idx & 63;
    dx[idx] = 0.5f * (xw_v[idx] * inv_deg_v[v] + Wbp[idx] * rsv[v] + gsb[c] + xw2_v[idx] + sgb[c]);
  } else {
    int j = idx - NV * 64;
    int g = j >> 6, c = j & 63;
    gx[j] = 0.5f * (xw_g[j] + gsb[c] + xw2_g[j] * inv_deg_g[g] + WbTp[j] * rsg[g] + sgb[c]);
  }
}

// =================================================================
extern "C" void kernel_launch(void* const* d_in, const int* in_sizes, int n_in,
                              void* d_out, int out_size, void* d_ws, size_t ws_size,
                              hipStream_t stream) {
  const float* vertices  = (const float*)d_in[0];
  const float* graph_pos = (const float*)d_in[1];
  const float* x_in      = (const float*)d_in[2];
  const float* graph_x   = (const float*)d_in[3];
  const float* mass      = (const float*)d_in[4];
  const float* evals     = (const float*)d_in[5];
  const float* evecs     = (const float*)d_in[6];
  const float* gradX     = (const float*)d_in[7];
  const float* gradY     = (const float*)d_in[8];
  const int*   eidx      = (const int*)d_in[9];
  const float* ew        = (const float*)d_in[10];
  const float* lin1_w    = (const float*)d_in[11];
  const float* lin1_b    = (const float*)d_in[12];
  const float* lin2_w    = (const float*)d_in[13];
  const float* lin2_b    = (const float*)d_in[14];
  const float* diff_time = (const float*)d_in[15];
  const float* A_re      = (const float*)d_in[16];
  const float* A_im      = (const float*)d_in[17];
  const float* mlp_w0    = (const float*)d_in[18];
  const float* mlp_b0    = (const float*)d_in[19];
  const float* mlp_w1    = (const float*)d_in[20];
  const float* mlp_b1    = (const float*)d_in[21];
  const float* mlp_w2    = (const float*)d_in[22];
  const float* mlp_b2    = (const float*)d_in[23];
  const float* gcn1_w    = (const float*)d_in[24];
  const float* gcn1_b    = (const float*)d_in[25];
  const float* gcn2_w    = (const float*)d_in[26];
  const float* gcn2_b    = (const float*)d_in[27];
  const float* gs_w      = (const float*)d_in[28];
  const float* gs_b      = (const float*)d_in[29];
  const float* sg_w      = (const float*)d_in[30];
  const float* sg_b      = (const float*)d_in[31];

  char* base = (char*)d_ws;
  size_t off = 0;
  auto alloc = [&](size_t nbytes) -> void* {
    void* p = base + off;
    off += (nbytes + 255) & ~(size_t)255;
    return p;
  };
  const size_t MBy = 1024 * 1024;
  u16*   Wb_bf   = (u16*)alloc((size_t)NV * NG * 2);        // 64 MB
  u16*   evecsT  = (u16*)alloc((size_t)128 * NV * 2);
  float* GXE2    = (float*)alloc((size_t)2 * NV * 128 * 4); // GXE | GYE contiguous
  float* GXE     = GXE2;
  float* GYE     = GXE2 + (size_t)NV * 128;
  float* sp      = (float*)alloc((size_t)NSLICE * 8192 * 4);
  float* Es      = (float*)alloc(8192 * 4);
  float* diffx   = (float*)alloc((size_t)NV * 64 * 4);
  float* gxb     = (float*)alloc((size_t)NG * 64 * 4);
  float* xd      = (float*)alloc((size_t)NV * 64 * 4);
  float* gf      = (float*)alloc((size_t)NV * 64 * 4);
  float* h1      = (float*)alloc((size_t)NV * 64 * 4);
  float* xw_v    = (float*)alloc((size_t)NV * 64 * 4);
  float* xw2_v   = (float*)alloc((size_t)NV * 64 * 4);
  float* xw_g    = (float*)alloc((size_t)NG * 64 * 4);
  float* xw2_g   = (float*)alloc((size_t)NG * 64 * 4);
  float* xw1     = (float*)alloc((size_t)NG * 64 * 4);
  float* xw2k    = (float*)alloc((size_t)NG * 64 * 4);
  u16*   xwgT    = (u16*)alloc((size_t)64 * NG * 2);
  u16*   xw2vT   = (u16*)alloc((size_t)64 * NV * 2);
  float* Wbp     = (float*)alloc((size_t)NV * 64 * 4);
  float* WbTp    = (float*)alloc((size_t)NG * 64 * 4);
  float* deg_v   = (float*)alloc(NV * 4);
  float* inv_deg_v = (float*)alloc(NV * 4);
  float* rsv     = (float*)alloc(NV * 4);
  float* deg_g   = (float*)alloc(NG * 4);
  float* inv_deg_g = (float*)alloc(NG * 4);
  float* rsg     = (float*)alloc(NG * 4);
  float* deg_e   = (float*)alloc(NG * 4);
  float* invdeg_e = (float*)alloc(NG * 4);
  float* dinv_e  = (float*)alloc(NG * 4);
  int*   cnt     = (int*)alloc(NG * 4);
  int*   row_ptr = (int*)alloc((NG + 1) * 4);
  int*   cursor  = (int*)alloc(NG * 4);
  int*   csr_src = (int*)alloc(NE * 4);
  float* csr_norm = (float*)alloc(NE * 4);

  // optional tiers: explicit WbT (64 MB) and larger parts for k-split
  size_t avail = ws_size > off ? ws_size - off : 0;
  u16* WbT_bf = nullptr;
  int nzHalf;
  size_t partsBytes;
  if (avail >= 129 * MBy)      { WbT_bf = (u16*)alloc((size_t)NG * NV * 2); partsBytes = 64 * MBy; nzHalf = 8; }
  else if (avail >= 97 * MBy)  { WbT_bf = (u16*)alloc((size_t)NG * NV * 2); partsBytes = 32 * MBy; nzHalf = 4; }
  else if (avail >= 81 * MBy)  { WbT_bf = (u16*)alloc((size_t)NG * NV * 2); partsBytes = 16 * MBy; nzHalf = 2; }
  else if (avail >= 33 * MBy)  { partsBytes = 32 * MBy; nzHalf = 4; }
  else                          { partsBytes = 16 * MBy; nzHalf = 2; }
  float* parts = (float*)alloc(partsBytes);
  if (off > ws_size) return;  // insufficient workspace -> fail loudly

  dim3 B256(256);

  // ---------- setup ----------
  k_fill4<<<dim3(80), B256, 0, stream>>>(deg_v, deg_g, deg_e, cnt);
  k_wb_build<<<dim3(128, 64), B256, 0, stream>>>(vertices, graph_pos, Wb_bf, WbT_bf, deg_v, deg_g);
  k_edge_prep<<<dim3(256), B256, 0, stream>>>(eidx, ew, deg_e, cnt);
  k_recips<<<dim3(64), B256, 0, stream>>>(deg_v, inv_deg_v, rsv, deg_g, inv_deg_g, rsg,
                                          deg_e, invdeg_e, dinv_e);
  k_scan<<<dim3(1), dim3(1024), 0, stream>>>(cnt, row_ptr, cursor);
  k_scatter<<<dim3(256), B256, 0, stream>>>(eidx, ew, dinv_e, cursor, csr_src, csr_norm);
  k_evecsT<<<dim3(256, 4), B256, 0, stream>>>(evecs, evecsT);
  // GXE = gradX @ evecs, GYE = gradY @ evecs (z-packed, k-split nzHalf each)
  gemm_setup<<<dim3(64, 1, 2 * nzHalf), B256, 0, stream>>>(
      gradX, gradY, evecsT, parts, nzHalf, 8192 / nzHalf);
  k_reduce2<<<dim3(2048), B256, 0, stream>>>(parts, GXE2, NV * 128, nzHalf);
  k_lin_both<<<dim3(3072), B256, 0, stream>>>(x_in, graph_x, lin1_w, lin1_b, lin2_w, lin2_b, diffx, gxb);

  // ---------- 4 blocks ----------
  for (int i = 0; i < 4; i++) {
    const float* dtrow = diff_time + i * 64;
    k_spec_part<<<dim3(128, NSLICE), dim3(64), 0, stream>>>(evecs, mass, diffx, sp);
    k_es<<<dim3(32), B256, 0, stream>>>(sp, evals, dtrow, Es);
    k_xdgf<<<dim3(2048), B256, 0, stream>>>(evecs, GXE, GYE, Es, A_re + i * 4096, A_im + i * 4096, xd, gf);
    k_mlp0<<<dim3(2048), B256, 0, stream>>>(diffx, xd, gf, mlp_w0 + i * 12288, mlp_b0 + i * 64, h1);
    k_mlp12<<<dim3(2048), B256, 0, stream>>>(h1, mlp_w1 + i * 4096, mlp_b1 + i * 64,
        mlp_w2 + i * 4096, mlp_b2 + i * 64, diffx);
    // graph GCN (2 convs) + graph-side dual projection
    k_mm64<false, false, false><<<dim3(1024), B256, 0, stream>>>(gxb, gcn1_w + i * 4096, nullptr, nullptr, xw1);
    k_aggmm<<<dim3(NG), dim3(64), 0, stream>>>(xw1, row_ptr, csr_src, csr_norm, invdeg_e,
        gcn1_b + i * 64, gcn2_w + i * 4096, xw2k);
    k_aggdual<<<dim3(NG), dim3(64), 0, stream>>>(xw2k, row_ptr, csr_src, csr_norm, invdeg_e,
        gcn2_b + i * 64, gs_w + i * 4096, sg_w + i * 4096, xw_g, xw2_g, xwgT);
    // vertex-side dual projection
    k_mm_dual<false, true><<<dim3(2048), B256, 0, stream>>>(diffx, gs_w + i * 4096, sg_w + i * 4096,
        xw_v, xw2_v, nullptr, xw2vT, NV);
    // Wbp = Wb @ xw_g  (M=NV, K=NG, ksplit 8)
    gemm_bf16<<<dim3(64, 1, 8), B256, 0, stream>>>(
        Wb_bf, NG, xwgT, NG, parts, NV, 512);
    k_reduce<<<dim3(512), B256, 0, stream>>>(parts, Wbp, NV * 64, 8);
    // WbTp = Wb^T @ xw2_v (M=NG, K=NV, ksplit 16)
    if (WbT_bf != nullptr) {
      gemm_bf16<<<dim3(32, 1, 16), B256, 0, stream>>>(
          WbT_bf, NV, xw2vT, NV, parts, NG, 512);
    } else {
      gemm_k<64, false, true><<<dim3(32, 1, 16), B256, 0, stream>>>(
          Wb_bf, nullptr, 1 << 30, xw2vT, parts, NG, 64, NG, NV, 512);
    }
    k_reduce<<<dim3(256), B256, 0, stream>>>(parts, WbTp, NG * 64, 16);
    // fused combine
    k_combine<<<dim3(3072), B256, 0, stream>>>(xw_v, Wbp, xw2_v, xw_g, WbTp, xw2_g,
        inv_deg_v, rsv, inv_deg_g, rsg, gs_b + i * 64, sg_b + i * 64, diffx, gxb);
  }

  hipMemcpyAsync(d_out, diffx, (size_t)NV * 64 * 4, hipMemcpyDeviceToDevice, stream);
}

// Round 5
// 1152.371 us; speedup vs baseline: 1.1773x; 1.0151x over previous
//
#include <hip/hip_runtime.h>
#include <hip/hip_bf16.h>

typedef unsigned short u16;
typedef __attribute__((ext_vector_type(8))) short sh8;     // 8 x bf16 (4 VGPRs)
typedef __attribute__((ext_vector_type(4))) float f32x4;   // MFMA accum

#define NV 8192
#define NG 4096
#define NE 65536
#define NSLICE 32

__device__ __forceinline__ u16 f2bf(float f) {
  __hip_bfloat16 h = __float2bfloat16(f);
  return __builtin_bit_cast(u16, h);
}

// async global->LDS, 16B per lane; LDS dest = wave-uniform base + lane*16
__device__ __forceinline__ void gl_lds16(const void* g, void* l) {
  __builtin_amdgcn_global_load_lds(
      (const __attribute__((address_space(1))) void*)g,
      (__attribute__((address_space(3))) void*)l, 16, 0, 0);
}

// ---------------- setup fills ----------------
__global__ void k_fill4(float* __restrict__ deg_v, float* __restrict__ deg_g,
                        float* __restrict__ deg_e, int* __restrict__ cnt) {
  int i = blockIdx.x * 256 + threadIdx.x;
  if (i < NV) deg_v[i] = 1.f;
  int j = i - NV;
  if (j >= 0 && j < NG) deg_g[j] = 1.f;
  j -= NG;
  if (j >= 0 && j < NG) deg_e[j] = 1.f;
  j -= NG;
  if (j >= 0 && j < NG) cnt[j] = 0;
}

// ---------------- Wb build: W = (d<8)?exp(-d/4):0, row/col sums, optional WbT
__global__ __launch_bounds__(256) void k_wb_build(
    const float* __restrict__ vert, const float* __restrict__ gpos,
    u16* __restrict__ Wb, u16* __restrict__ WbT,
    float* __restrict__ deg_v, float* __restrict__ deg_g) {
  __shared__ float lv[192], lg[192], colp[256];
  __shared__ float tile[64][65];
  int t = threadIdx.x;
  int v0 = blockIdx.x * 64, g0 = blockIdx.y * 64;
  if (t < 192) { lv[t] = vert[(size_t)v0 * 3 + t]; lg[t] = gpos[(size_t)g0 * 3 + t]; }
  __syncthreads();
  int w = t >> 6, lane = t & 63;
  float gx_ = lg[lane * 3], gy_ = lg[lane * 3 + 1], gz_ = lg[lane * 3 + 2];
  float csum = 0.f;
  #pragma unroll 4
  for (int s = 0; s < 16; s++) {
    int vl = w + 4 * s;
    float dx = lv[vl * 3] - gx_, dy = lv[vl * 3 + 1] - gy_, dz = lv[vl * 3 + 2] - gz_;
    float d = sqrtf(dx * dx + dy * dy + dz * dz);
    float W = (d < 8.0f) ? expf(d * -0.25f) : 0.f;
    Wb[(size_t)(v0 + vl) * NG + g0 + lane] = f2bf(W);
    tile[vl][lane] = W;
    csum += W;
  }
  colp[t] = csum;
  __syncthreads();
  // row sums: 4 threads per row
  int r = t >> 2, q = t & 3;
  float rs = 0.f;
  #pragma unroll
  for (int j = 0; j < 16; j++) rs += tile[r][q * 16 + j];
  rs += __shfl_xor(rs, 1);
  rs += __shfl_xor(rs, 2);
  if (q == 0) atomicAdd(&deg_v[v0 + r], rs);
  if (w == 0) {
    float tot = colp[lane] + colp[64 + lane] + colp[128 + lane] + colp[192 + lane];
    atomicAdd(&deg_g[g0 + lane], tot);
  }
  if (WbT != nullptr) {
    #pragma unroll
    for (int j = 0; j < 2; j++) {
      int idx = j * 256 + t;
      int g = idx >> 3, v8 = (idx & 7) * 8;
      u16 pk[8];
      #pragma unroll
      for (int qq = 0; qq < 8; qq++) pk[qq] = f2bf(tile[v8 + qq][g]);
      *(uint4*)&WbT[(size_t)(g0 + g) * NV + v0 + v8] = *(uint4*)pk;
    }
  }
}

// all three recips in one launch
__global__ void k_recips(const float* __restrict__ deg_v, float* __restrict__ inv_v,
                         float* __restrict__ rs_v, const float* __restrict__ deg_g,
                         float* __restrict__ inv_g, float* __restrict__ rs_g,
                         const float* __restrict__ deg_e, float* __restrict__ inv_e,
                         float* __restrict__ rs_e) {
  int i = blockIdx.x * 256 + threadIdx.x;
  if (i < NV) { float d = deg_v[i]; inv_v[i] = 1.f / d; rs_v[i] = 1.f / sqrtf(d); }
  else if (i < NV + NG) {
    int j = i - NV; float d = deg_g[j]; inv_g[j] = 1.f / d; rs_g[j] = 1.f / sqrtf(d);
  } else if (i < NV + 2 * NG) {
    int j = i - NV - NG; float d = deg_e[j]; inv_e[j] = 1.f / d; rs_e[j] = 1.f / sqrtf(d);
  }
}

// ---------------- edge preprocessing (CSR) ----------------
__global__ void k_edge_prep(const int* __restrict__ eidx, const float* __restrict__ ew,
                            float* __restrict__ deg_e, int* __restrict__ cnt) {
  int e = blockIdx.x * 256 + threadIdx.x;
  if (e < NE) { int d = eidx[NE + e]; atomicAdd(&deg_e[d], ew[e]); atomicAdd(&cnt[d], 1); }
}

__global__ __launch_bounds__(1024) void k_scan(const int* __restrict__ cnt,
    int* __restrict__ row_ptr, int* __restrict__ cursor) {
  __shared__ int buf0[1024], buf1[1024];
  int t = threadIdx.x;
  int b = t * 4;
  int c0 = cnt[b], c1 = cnt[b + 1], c2 = cnt[b + 2], c3 = cnt[b + 3];
  int s = c0 + c1 + c2 + c3;
  buf0[t] = s;
  __syncthreads();
  int* src = buf0; int* dst = buf1;
  for (int off = 1; off < 1024; off <<= 1) {
    int v = src[t];
    if (t >= off) v += src[t - off];
    dst[t] = v;
    __syncthreads();
    int* tmp = src; src = dst; dst = tmp;
  }
  int excl = (t == 0) ? 0 : src[t - 1];
  int r0 = excl, r1 = excl + c0, r2 = excl + c0 + c1, r3 = excl + c0 + c1 + c2;
  row_ptr[b] = r0; row_ptr[b + 1] = r1; row_ptr[b + 2] = r2; row_ptr[b + 3] = r3;
  cursor[b] = r0; cursor[b + 1] = r1; cursor[b + 2] = r2; cursor[b + 3] = r3;
  if (t == 1023) row_ptr[4096] = src[1023];
}

__global__ void k_scatter(const int* __restrict__ eidx, const float* __restrict__ ew,
                          const float* __restrict__ dinv, int* __restrict__ cursor,
                          int* __restrict__ csrc, float* __restrict__ cnorm) {
  int e = blockIdx.x * 256 + threadIdx.x;
  if (e < NE) {
    int s = eidx[e], d = eidx[NE + e];
    int slot = atomicAdd(&cursor[d], 1);
    csrc[slot] = s;
    cnorm[slot] = dinv[s] * ew[e] * dinv[d];
  }
}

// ---------------- evecs -> bf16 transposed [128][NV] ----------------
__global__ __launch_bounds__(256) void k_evecsT(const float* __restrict__ ev, u16* __restrict__ evT) {
  __shared__ float tile[32][33];
  int t = threadIdx.x;
  int v0 = blockIdx.x * 32, k0 = blockIdx.y * 32;
  int r = t >> 3, c4 = (t & 7) * 4;
  float4 x = *(const float4*)(ev + (size_t)(v0 + r) * 128 + k0 + c4);
  tile[r][c4] = x.x; tile[r][c4 + 1] = x.y; tile[r][c4 + 2] = x.z; tile[r][c4 + 3] = x.w;
  __syncthreads();
  u16* dst = evT + (size_t)(k0 + r) * NV + v0 + c4;
  dst[0] = f2bf(tile[c4][r]); dst[1] = f2bf(tile[c4 + 1][r]);
  dst[2] = f2bf(tile[c4 + 2][r]); dst[3] = f2bf(tile[c4 + 3][r]);
}

// =============== setup GEMM: [GXE|GYE] = [gradX|gradY](fp32) @ evecsT^T =====
// BM=128, BN=128, BK=32. A staged to LDS as fp32 via global_load_lds with
// XOR-swizzled source; bf16 convert after ds_read. 2 buffers, 2 tiles in
// flight via counted vmcnt (T4): per wave exactly 6 loads per tile.
__global__ __launch_bounds__(256) void gemm_setup(
    const float* __restrict__ gXm, const float* __restrict__ gYm,
    const u16* __restrict__ evT, float* __restrict__ parts,
    int nzHalf, int kchunk) {
  __shared__ __align__(16) char smem[49152];   // 2 x (A 16KB fp32 + B 8KB bf16)
  const int t = threadIdx.x;
  const int lane = t & 63, wave = t >> 6;
  const int m0 = blockIdx.x * 128;
  int kz = blockIdx.z;
  const float* A = gXm;
  if (kz >= nzHalf) { A = gYm; kz -= nzHalf; }
  const int kbeg = kz * kchunk;
  const int nt = kchunk >> 5;
  const int wm = (wave >> 1) * 64, wn = (wave & 1) * 64;
  const int arl = lane >> 3, asl = lane & 7;   // A: 8 rows/instr, 8x16B slots/row
  const int brl = lane >> 2, bsl = lane & 3;   // B: 16 rows/instr, 4x16B slots/row

  f32x4 acc[4][4];
  #pragma unroll
  for (int a = 0; a < 4; a++)
    #pragma unroll
    for (int b = 0; b < 4; b++) acc[a][b] = f32x4{0.f, 0.f, 0.f, 0.f};

  auto STAGE = [&](int buf, int k0) {   // exactly 6 gl_lds16 per wave
    char* base = smem + buf * 24576;
    #pragma unroll
    for (int j = 0; j < 4; j++) {
      int R0 = (wave * 4 + j) * 8;
      int r = R0 + arl;
      int gs = asl ^ (r & 7);
      gl_lds16(A + (size_t)(m0 + r) * NV + k0 + gs * 4, base + R0 * 128);
    }
    char* bb = base + 16384;
    #pragma unroll
    for (int j = 0; j < 2; j++) {
      int R0 = (wave * 2 + j) * 16;
      int r = R0 + brl;
      int gs = bsl ^ (r & 3);
      gl_lds16(evT + (size_t)r * NV + k0 + gs * 8, bb + R0 * 64);
    }
  };

  auto COMPUTE = [&](int buf) {
    char* base = smem + buf * 24576;
    const float* Af = (const float*)base;
    const u16* Bf = (const u16*)(base + 16384);
    sh8 av[4], bv[4];
    #pragma unroll
    for (int mf = 0; mf < 4; mf++) {
      int r = wm + mf * 16 + (lane & 15);
      int b2 = (lane >> 4) * 2;
      float4 f0 = *(const float4*)(Af + r * 32 + ((b2) ^ (r & 7)) * 4);
      float4 f1 = *(const float4*)(Af + r * 32 + ((b2 + 1) ^ (r & 7)) * 4);
      sh8 v;
      v[0] = (short)f2bf(f0.x); v[1] = (short)f2bf(f0.y);
      v[2] = (short)f2bf(f0.z); v[3] = (short)f2bf(f0.w);
      v[4] = (short)f2bf(f1.x); v[5] = (short)f2bf(f1.y);
      v[6] = (short)f2bf(f1.z); v[7] = (short)f2bf(f1.w);
      av[mf] = v;
    }
    #pragma unroll
    for (int nf = 0; nf < 4; nf++) {
      int r = wn + nf * 16 + (lane & 15);
      int s = (lane >> 4) ^ (r & 3);
      bv[nf] = *(const sh8*)(Bf + r * 32 + s * 8);
    }
    #pragma unroll
    for (int mf = 0; mf < 4; mf++)
      #pragma unroll
      for (int nf = 0; nf < 4; nf++)
        acc[mf][nf] = __builtin_amdgcn_mfma_f32_16x16x32_bf16(av[mf], bv[nf], acc[mf][nf], 0, 0, 0);
  };

  STAGE(0, kbeg);
  if (nt > 1) STAGE(1, kbeg + 32);
  for (int ti = 0; ti < nt; ti++) {
    if (ti + 1 < nt) { asm volatile("s_waitcnt vmcnt(6)" ::: "memory"); }
    else             { asm volatile("s_waitcnt vmcnt(0)" ::: "memory"); }
    __builtin_amdgcn_sched_barrier(0);
    __builtin_amdgcn_s_barrier();
    COMPUTE(ti & 1);
    __builtin_amdgcn_sched_barrier(0);
    __builtin_amdgcn_s_barrier();
    if (ti + 2 < nt) STAGE(ti & 1, kbeg + (ti + 2) * 32);
  }

  float* C = parts + (size_t)blockIdx.z * (NV * 128);
  #pragma unroll
  for (int mf = 0; mf < 4; mf++)
    #pragma unroll
    for (int nf = 0; nf < 4; nf++) {
      int row = m0 + wm + mf * 16 + (lane >> 4) * 4;
      int col = wn + nf * 16 + (lane & 15);
      #pragma unroll
      for (int q = 0; q < 4; q++)
        C[(size_t)(row + q) * 128 + col] = acc[mf][nf][q];
    }
}

// =============== bf16 GEMM (Wb / WbT products): C = A @ BT^T, N=64 ==========
// BM=128, BN=64, BK=64; counted-vmcnt 2-tile pipeline (6 loads/wave/tile).
__global__ __launch_bounds__(256) void gemm_bf16(
    const u16* __restrict__ Ab, int lda, const u16* __restrict__ BT, int ldbt,
    float* __restrict__ parts, int M, int kchunk) {
  __shared__ __align__(16) char smem[49152];   // 2 x (A 16KB + B 8KB)
  const int t = threadIdx.x;
  const int lane = t & 63, wave = t >> 6;
  const int m0 = blockIdx.x * 128;
  const int kbeg = blockIdx.z * kchunk;
  const int nt = kchunk >> 6;
  const int wm = (wave >> 1) * 64, wn = (wave & 1) * 32;
  const int arl = lane >> 3, asl = lane & 7;

  f32x4 acc[4][2];
  #pragma unroll
  for (int a = 0; a < 4; a++)
    #pragma unroll
    for (int b = 0; b < 2; b++) acc[a][b] = f32x4{0.f, 0.f, 0.f, 0.f};

  auto STAGE = [&](int buf, int k0) {   // exactly 6 gl_lds16 per wave
    char* base = smem + buf * 24576;
    #pragma unroll
    for (int j = 0; j < 4; j++) {
      int R0 = (wave * 4 + j) * 8;
      int r = R0 + arl;
      int gs = asl ^ (r & 7);
      gl_lds16(Ab + (size_t)(m0 + r) * lda + k0 + gs * 8, base + R0 * 128);
    }
    char* bb = base + 16384;
    #pragma unroll
    for (int j = 0; j < 2; j++) {
      int R0 = (wave * 2 + j) * 8;
      int r = R0 + arl;
      int gs = asl ^ (r & 7);
      gl_lds16(BT + (size_t)r * ldbt + k0 + gs * 8, bb + R0 * 128);
    }
  };

  auto COMPUTE = [&](int buf) {
    char* base = smem + buf * 24576;
    const u16* Af = (const u16*)base;
    const u16* Bf = (const u16*)(base + 16384);
    #pragma unroll
    for (int kk = 0; kk < 2; kk++) {
      sh8 av[4], bv[2];
      #pragma unroll
      for (int mf = 0; mf < 4; mf++) {
        int r = wm + mf * 16 + (lane & 15);
        int g = kk * 4 + (lane >> 4);
        av[mf] = *(const sh8*)(Af + r * 64 + (g ^ (r & 7)) * 8);
      }
      #pragma unroll
      for (int nf = 0; nf < 2; nf++) {
        int r = wn + nf * 16 + (lane & 15);
        int g = kk * 4 + (lane >> 4);
        bv[nf] = *(const sh8*)(Bf + r * 64 + (g ^ (r & 7)) * 8);
      }
      #pragma unroll
      for (int mf = 0; mf < 4; mf++)
        #pragma unroll
        for (int nf = 0; nf < 2; nf++)
          acc[mf][nf] = __builtin_amdgcn_mfma_f32_16x16x32_bf16(av[mf], bv[nf], acc[mf][nf], 0, 0, 0);
    }
  };

  STAGE(0, kbeg);
  if (nt > 1) STAGE(1, kbeg + 64);
  for (int ti = 0; ti < nt; ti++) {
    if (ti + 1 < nt) { asm volatile("s_waitcnt vmcnt(6)" ::: "memory"); }
    else             { asm volatile("s_waitcnt vmcnt(0)" ::: "memory"); }
    __builtin_amdgcn_sched_barrier(0);
    __builtin_amdgcn_s_barrier();
    COMPUTE(ti & 1);
    __builtin_amdgcn_sched_barrier(0);
    __builtin_amdgcn_s_barrier();
    if (ti + 2 < nt) STAGE(ti & 1, kbeg + (ti + 2) * 64);
  }

  float* C = parts + (size_t)blockIdx.z * M * 64;
  #pragma unroll
  for (int mf = 0; mf < 4; mf++)
    #pragma unroll
    for (int nf = 0; nf < 2; nf++) {
      int row = m0 + wm + mf * 16 + (lane >> 4) * 4;
      int col = wn + nf * 16 + (lane & 15);
      #pragma unroll
      for (int q = 0; q < 4; q++)
        C[(size_t)(row + q) * 64 + col] = acc[mf][nf][q];
    }
}

// ---------------- round-2 GEMM kept ONLY as low-ws ATRANS fallback ----------
template<int BN, bool AF32, bool ATRANS>
__global__ __launch_bounds__(256) void gemm_k(
    const void* __restrict__ Aptr, const void* __restrict__ A2, int zsplit2,
    const u16* __restrict__ BT, float* __restrict__ Cpart,
    int M, int N, int lda, int ldbt, int kchunk) {
  constexpr int NF = BN / 32;
  __shared__ u16 lA[128 * 40];
  __shared__ u16 lB[BN * 40];
  const int t = threadIdx.x;
  const int m0 = blockIdx.x * 128, n0 = blockIdx.y * BN;
  const void* Ause = Aptr;
  int kz = blockIdx.z;
  if (A2 != nullptr && kz >= zsplit2) { Ause = A2; kz -= zsplit2; }
  const int kbeg = kz * kchunk;
  const int lane = t & 63, wave = t >> 6;
  const int wm = (wave >> 1) * 64, wn = (wave & 1) * (BN / 2);
  f32x4 zero = {0.f, 0.f, 0.f, 0.f};
  f32x4 acc[4][NF];
  #pragma unroll
  for (int a = 0; a < 4; a++)
    #pragma unroll
    for (int b = 0; b < NF; b++) acc[a][b] = zero;

  for (int k0 = kbeg; k0 < kbeg + kchunk; k0 += 32) {
    if constexpr (!ATRANS) {
      const int r = t >> 1, cc = (t & 1) * 16;
      const u16* A = (const u16*)Ause + (size_t)(m0 + r) * lda + k0 + cc;
      *(uint4*)&lA[r * 40 + cc] = *(const uint4*)A;
      *(uint4*)&lA[r * 40 + cc + 8] = *(const uint4*)(A + 8);
    } else {
      const int kl = t >> 3, mb = (t & 7) * 16;
      const u16* A = (const u16*)Ause + (size_t)(k0 + kl) * lda + m0 + mb;
      u16 vals[16];
      *(uint4*)&vals[0] = *(const uint4*)A;
      *(uint4*)&vals[8] = *(const uint4*)(A + 8);
      #pragma unroll
      for (int j = 0; j < 16; j++) lA[(mb + j) * 40 + kl] = vals[j];
    }
    if constexpr (BN == 64) {
      const int r = t >> 2, cc = (t & 3) * 8;
      const u16* B = BT + (size_t)(n0 + r) * ldbt + k0 + cc;
      *(uint4*)&lB[r * 40 + cc] = *(const uint4*)B;
    } else {
      const int r = t >> 1, cc = (t & 1) * 16;
      const u16* B = BT + (size_t)(n0 + r) * ldbt + k0 + cc;
      *(uint4*)&lB[r * 40 + cc] = *(const uint4*)B;
      *(uint4*)&lB[r * 40 + cc + 8] = *(const uint4*)(B + 8);
    }
    __syncthreads();
    sh8 af[4], bfv[NF];
    #pragma unroll
    for (int mf = 0; mf < 4; mf++)
      af[mf] = *(const sh8*)&lA[(wm + mf * 16 + (lane & 15)) * 40 + (lane >> 4) * 8];
    #pragma unroll
    for (int nf = 0; nf < NF; nf++)
      bfv[nf] = *(const sh8*)&lB[(wn + nf * 16 + (lane & 15)) * 40 + (lane >> 4) * 8];
    #pragma unroll
    for (int mf = 0; mf < 4; mf++)
      #pragma unroll
      for (int nf = 0; nf < NF; nf++)
        acc[mf][nf] = __builtin_amdgcn_mfma_f32_16x16x32_bf16(af[mf], bfv[nf], acc[mf][nf], 0, 0, 0);
    __syncthreads();
  }
  float* C = Cpart + (size_t)blockIdx.z * M * N;
  #pragma unroll
  for (int mf = 0; mf < 4; mf++)
    #pragma unroll
    for (int nf = 0; nf < NF; nf++) {
      const int row = m0 + wm + mf * 16 + (lane >> 4) * 4;
      const int col = n0 + wn + nf * 16 + (lane & 15);
      #pragma unroll
      for (int q = 0; q < 4; q++)
        C[(size_t)(row + q) * N + col] = acc[mf][nf][q];
    }
}

__global__ void k_reduce(const float* __restrict__ parts, float* __restrict__ dst, int len, int nz) {
  int i = (blockIdx.x * 256 + threadIdx.x) * 4;
  if (i >= len) return;
  float4 s = *(const float4*)(parts + i);
  for (int z = 1; z < nz; z++) {
    float4 v = *(const float4*)(parts + (size_t)z * len + i);
    s.x += v.x; s.y += v.y; s.z += v.z; s.w += v.w;
  }
  *(float4*)(dst + i) = s;
}

// two matrices packed: dst[mat*len + j] = sum_z parts[(mat*nz+z)*len + j]
__global__ void k_reduce2(const float* __restrict__ parts, float* __restrict__ dst, int len, int nz) {
  int i = (blockIdx.x * 256 + threadIdx.x) * 4;
  if (i >= 2 * len) return;
  int mat = i / len, j = i - mat * len;
  const float* src = parts + (size_t)mat * nz * len + j;
  float4 s = *(const float4*)src;
  for (int z = 1; z < nz; z++) {
    float4 v = *(const float4*)(src + (size_t)z * len);
    s.x += v.x; s.y += v.y; s.z += v.z; s.w += v.w;
  }
  *(float4*)(dst + i) = s;
}

// ---------------- fused lin1/lin2 (C_IN=128 -> DW=64) ----------------
__global__ __launch_bounds__(256) void k_lin_both(const float* __restrict__ x_in,
    const float* __restrict__ graph_x, const float* __restrict__ W1,
    const float* __restrict__ b1, const float* __restrict__ W2,
    const float* __restrict__ b2, float* __restrict__ outV, float* __restrict__ outG) {
  __shared__ float lW[8192];
  __shared__ float lb[64];
  int bb = blockIdx.x;
  bool isV = bb < 2048;
  const float* W = isV ? W1 : W2;
  const float* bi = isV ? b1 : b2;
  const float* A = isV ? x_in : graph_x;
  float* out = isV ? outV : outG;
  int rb = isV ? bb : bb - 2048;
  int t = threadIdx.x;
  for (int i = t; i < 8192; i += 256) lW[i] = W[i];
  if (t < 64) lb[t] = bi[t];
  __syncthreads();
  int row = rb * 4 + (t >> 6), c = t & 63;
  const float* Ar = A + (size_t)row * 128;
  float acc = lb[c];
  #pragma unroll 8
  for (int k = 0; k < 128; k++) acc += Ar[k] * lW[k * 64 + c];
  out[(size_t)row * 64 + c] = acc;
}

// ---------------- spectral: sliced partial sums, no atomics ----------------
__global__ __launch_bounds__(64) void k_spec_part(const float* __restrict__ evecs,
    const float* __restrict__ mass, const float* __restrict__ dx, float* __restrict__ sp) {
  int k = blockIdx.x, c = threadIdx.x;
  int v0 = blockIdx.y * 256;
  float a0 = 0, a1 = 0, a2 = 0, a3 = 0;
  for (int v = v0; v < v0 + 256; v += 4) {
    a0 += evecs[(size_t)(v + 0) * 128 + k] * mass[v + 0] * dx[(size_t)(v + 0) * 64 + c];
    a1 += evecs[(size_t)(v + 1) * 128 + k] * mass[v + 1] * dx[(size_t)(v + 1) * 64 + c];
    a2 += evecs[(size_t)(v + 2) * 128 + k] * mass[v + 2] * dx[(size_t)(v + 2) * 64 + c];
    a3 += evecs[(size_t)(v + 3) * 128 + k] * mass[v + 3] * dx[(size_t)(v + 3) * 64 + c];
  }
  sp[(size_t)blockIdx.y * 8192 + k * 64 + c] = (a0 + a1) + (a2 + a3);
}

// Es[k][c] = exp(-evals[k]*t[c]) * sum_z sp[z][k][c]
__global__ void k_es(const float* __restrict__ sp, const float* __restrict__ evals,
                     const float* __restrict__ dt, float* __restrict__ Es) {
  int i = blockIdx.x * 256 + threadIdx.x;
  int k = i >> 6, c = i & 63;
  float s = 0.f;
  #pragma unroll 8
  for (int z = 0; z < NSLICE; z++) s += sp[(size_t)z * 8192 + i];
  Es[i] = expf(-evals[k] * fmaxf(dt[c], 1e-8f)) * s;
}

// ---------------- fused xd + gradient features ----------------
__global__ __launch_bounds__(256) void k_xdgf(const float* __restrict__ evecs,
    const float* __restrict__ GXE, const float* __restrict__ GYE,
    const float* __restrict__ Es, const float* __restrict__ Are,
    const float* __restrict__ Aim, float* __restrict__ xd, float* __restrict__ gf) {
  __shared__ float lE[8192];
  __shared__ float lr[4096], li[4096];
  __shared__ float lgx[256], lgy[256];
  int t = threadIdx.x;
  for (int i = t; i < 8192; i += 256) lE[i] = Es[i];
  for (int i = t; i < 4096; i += 256) { lr[i] = Are[i]; li[i] = Aim[i]; }
  __syncthreads();
  int wr = t >> 6, c = t & 63;
  int row = blockIdx.x * 4 + wr;
  const float* er = evecs + (size_t)row * 128;
  const float* xr = GXE + (size_t)row * 128;
  const float* yr = GYE + (size_t)row * 128;
  float a0 = 0, a1 = 0, a2 = 0;
  #pragma unroll 8
  for (int k = 0; k < 128; k++) {
    float s = lE[k * 64 + c];
    a0 += er[k] * s; a1 += xr[k] * s; a2 += yr[k] * s;
  }
  lgx[wr * 64 + c] = a1;
  lgy[wr * 64 + c] = a2;
  __syncthreads();
  float br = 0.f, bi = 0.f;
  #pragma unroll 8
  for (int k = 0; k < 64; k++) {
    float gx = lgx[wr * 64 + k], gy = lgy[wr * 64 + k];
    float ar = lr[k * 64 + c], ai = li[k * 64 + c];
    br += gx * ar - gy * ai;
    bi += gy * ar + gx * ai;
  }
  xd[(size_t)row * 64 + c] = a0;
  gf[(size_t)row * 64 + c] = tanhf(a1 * br + a2 * bi);
}

__global__ __launch_bounds__(256) void k_mlp0(const float* __restrict__ dx,
    const float* __restrict__ xd, const float* __restrict__ gf,
    const float* __restrict__ W0, const float* __restrict__ b0, float* __restrict__ h1) {
  __shared__ float lW[12288];
  __shared__ float lb[64];
  int t = threadIdx.x;
  for (int i = t; i < 12288; i += 256) lW[i] = W0[i];
  if (t < 64) lb[t] = b0[t];
  __syncthreads();
  int row = blockIdx.x * 4 + (t >> 6), c = t & 63;
  const float* a0 = dx + (size_t)row * 64;
  const float* a1 = xd + (size_t)row * 64;
  const float* a2 = gf + (size_t)row * 64;
  float acc = lb[c];
  #pragma unroll 8
  for (int k = 0; k < 64; k++) acc += a0[k] * lW[k * 64 + c];
  #pragma unroll 8
  for (int k = 0; k < 64; k++) acc += a1[k] * lW[(64 + k) * 64 + c];
  #pragma unroll 8
  for (int k = 0; k < 64; k++) acc += a2[k] * lW[(128 + k) * 64 + c];
  h1[(size_t)row * 64 + c] = fmaxf(acc, 0.f);
}

// fused mlp1 + mlp2 + residual: dx += relu(h1@W1+b1)@W2 + b2
__global__ __launch_bounds__(256) void k_mlp12(const float* __restrict__ h1,
    const float* __restrict__ W1, const float* __restrict__ b1,
    const float* __restrict__ W2, const float* __restrict__ b2, float* __restrict__ dx) {
  __shared__ float l1[4096], l2[4096], lb1[64], lb2[64], lrow[256];
  int t = threadIdx.x;
  for (int i = t; i < 4096; i += 256) { l1[i] = W1[i]; l2[i] = W2[i]; }
  if (t < 64) lb1[t] = b1[t];
  else if (t < 128) lb2[t - 64] = b2[t - 64];
  __syncthreads();
  int wr = t >> 6, c = t & 63;
  int row = blockIdx.x * 4 + wr;
  const float* hr = h1 + (size_t)row * 64;
  float h2 = lb1[c];
  #pragma unroll 8
  for (int k = 0; k < 64; k++) h2 += hr[k] * l1[k * 64 + c];
  h2 = fmaxf(h2, 0.f);
  lrow[wr * 64 + c] = h2;
  __syncthreads();
  float o = lb2[c] + dx[(size_t)row * 64 + c];
  #pragma unroll 8
  for (int k = 0; k < 64; k++) o += lrow[wr * 64 + k] * l2[k * 64 + c];
  dx[(size_t)row * 64 + c] = o;
}

// ---------------- small fp32 matmul (64x64 weights) ----------------
template<bool BIAS, bool RELU, bool RES>
__global__ __launch_bounds__(256) void k_mm64(const float* __restrict__ A,
    const float* __restrict__ W, const float* __restrict__ b,
    const float* __restrict__ res, float* __restrict__ out) {
  __shared__ float lW[4096];
  __shared__ float lb[64];
  int t = threadIdx.x;
  for (int i = t; i < 4096; i += 256) lW[i] = W[i];
  if constexpr (BIAS) { if (t < 64) lb[t] = b[t]; }
  __syncthreads();
  int row = blockIdx.x * 4 + (t >> 6), c = t & 63;
  const float* Ar = A + (size_t)row * 64;
  float acc = 0.f;
  #pragma unroll 8
  for (int k = 0; k < 64; k++) acc += Ar[k] * lW[k * 64 + c];
  if constexpr (BIAS) acc += lb[c];
  if constexpr (RES) acc += res[(size_t)row * 64 + c];
  if constexpr (RELU) acc = fmaxf(acc, 0.f);
  out[(size_t)row * 64 + c] = acc;
}

template<bool TP, bool TQ>
__global__ __launch_bounds__(256) void k_mm_dual(const float* __restrict__ A,
    const float* __restrict__ W1, const float* __restrict__ W2,
    float* __restrict__ P, float* __restrict__ Q,
    u16* __restrict__ PT, u16* __restrict__ QT, int R) {
  __shared__ float l1[4096], l2[4096];
  int t = threadIdx.x;
  for (int i = t; i < 4096; i += 256) { l1[i] = W1[i]; l2[i] = W2[i]; }
  __syncthreads();
  int row = blockIdx.x * 4 + (t >> 6), c = t & 63;
  const float* Ar = A + (size_t)row * 64;
  float p = 0.f, q = 0.f;
  #pragma unroll 8
  for (int k = 0; k < 64; k++) { float a = Ar[k]; p += a * l1[k * 64 + c]; q += a * l2[k * 64 + c]; }
  P[(size_t)row * 64 + c] = p;
  Q[(size_t)row * 64 + c] = q;
  if constexpr (TP) PT[(size_t)c * R + row] = f2bf(p);
  if constexpr (TQ) QT[(size_t)c * R + row] = f2bf(q);
}

// ---------------- GCN agg + next matmul fused ----------------
__global__ __launch_bounds__(64) void k_aggmm(const float* __restrict__ xw,
    const int* __restrict__ rp, const int* __restrict__ csrc,
    const float* __restrict__ cnorm, const float* __restrict__ invdeg,
    const float* __restrict__ b1, const float* __restrict__ W2, float* __restrict__ out) {
  __shared__ float lrow[64];
  int g = blockIdx.x, c = threadIdx.x;
  float acc = xw[(size_t)g * 64 + c] * invdeg[g] + b1[c];
  int j1 = rp[g + 1];
  for (int j = rp[g]; j < j1; j++) acc += cnorm[j] * xw[(size_t)csrc[j] * 64 + c];
  acc = fmaxf(acc, 0.f);
  lrow[c] = acc;
  __syncthreads();
  float o = 0.f;
  #pragma unroll 8
  for (int k = 0; k < 64; k++) o += lrow[k] * W2[k * 64 + c];
  out[(size_t)g * 64 + c] = o;
}

__global__ __launch_bounds__(64) void k_aggdual(const float* __restrict__ xw,
    const int* __restrict__ rp, const int* __restrict__ csrc,
    const float* __restrict__ cnorm, const float* __restrict__ invdeg,
    const float* __restrict__ b2, const float* __restrict__ gsw,
    const float* __restrict__ sgw, float* __restrict__ xw_g,
    float* __restrict__ xw2_g, u16* __restrict__ xwgT) {
  __shared__ float lrow[64];
  int g = blockIdx.x, c = threadIdx.x;
  float acc = xw[(size_t)g * 64 + c] * invdeg[g] + b2[c];
  int j1 = rp[g + 1];
  for (int j = rp[g]; j < j1; j++) acc += cnorm[j] * xw[(size_t)csrc[j] * 64 + c];
  lrow[c] = acc;
  __syncthreads();
  float p = 0.f, q = 0.f;
  #pragma unroll 8
  for (int k = 0; k < 64; k++) {
    float r = lrow[k];
    p += r * gsw[k * 64 + c];
    q += r * sgw[k * 64 + c];
  }
  xw_g[(size_t)g * 64 + c] = p;
  xw2_g[(size_t)g * 64 + c] = q;
  xwgT[(size_t)c * NG + g] = f2bf(p);
}

// ---------------- fused bipartite combine ----------------
__global__ void k_combine(const float* __restrict__ xw_v, const float* __restrict__ Wbp,
    const float* __restrict__ xw2_v, const float* __restrict__ xw_g,
    const float* __restrict__ WbTp, const float* __restrict__ xw2_g,
    const float* __restrict__ inv_deg_v, const float* __restrict__ rsv,
    const float* __restrict__ inv_deg_g, const float* __restrict__ rsg,
    const float* __restrict__ gsb, const float* __restrict__ sgb,
    float* __restrict__ dx, float* __restrict__ gx) {
  int idx = blockIdx.x * 256 + threadIdx.x;
  if (idx < NV * 64) {
    int v = idx >> 6, c = idx & 63;
    dx[idx] = 0.5f * (xw_v[idx] * inv_deg_v[v] + Wbp[idx] * rsv[v] + gsb[c] + xw2_v[idx] + sgb[c]);
  } else {
    int j = idx - NV * 64;
    int g = j >> 6, c = j & 63;
    gx[j] = 0.5f * (xw_g[j] + gsb[c] + xw2_g[j] * inv_deg_g[g] + WbTp[j] * rsg[g] + sgb[c]);
  }
}

// =================================================================
extern "C" void kernel_launch(void* const* d_in, const int* in_sizes, int n_in,
                              void* d_out, int out_size, void* d_ws, size_t ws_size,
                              hipStream_t stream) {
  const float* vertices  = (const float*)d_in[0];
  const float* graph_pos = (const float*)d_in[1];
  const float* x_in      = (const float*)d_in[2];
  const float* graph_x   = (const float*)d_in[3];
  const float* mass      = (const float*)d_in[4];
  const float* evals     = (const float*)d_in[5];
  const float* evecs     = (const float*)d_in[6];
  const float* gradX     = (const float*)d_in[7];
  const float* gradY     = (const float*)d_in[8];
  const int*   eidx      = (const int*)d_in[9];
  const float* ew        = (const float*)d_in[10];
  const float* lin1_w    = (const float*)d_in[11];
  const float* lin1_b    = (const float*)d_in[12];
  const float* lin2_w    = (const float*)d_in[13];
  const float* lin2_b    = (const float*)d_in[14];
  const float* diff_time = (const float*)d_in[15];
  const float* A_re      = (const float*)d_in[16];
  const float* A_im      = (const float*)d_in[17];
  const float* mlp_w0    = (const float*)d_in[18];
  const float* mlp_b0    = (const float*)d_in[19];
  const float* mlp_w1    = (const float*)d_in[20];
  const float* mlp_b1    = (const float*)d_in[21];
  const float* mlp_w2    = (const float*)d_in[22];
  const float* mlp_b2    = (const float*)d_in[23];
  const float* gcn1_w    = (const float*)d_in[24];
  const float* gcn1_b    = (const float*)d_in[25];
  const float* gcn2_w    = (const float*)d_in[26];
  const float* gcn2_b    = (const float*)d_in[27];
  const float* gs_w      = (const float*)d_in[28];
  const float* gs_b      = (const float*)d_in[29];
  const float* sg_w      = (const float*)d_in[30];
  const float* sg_b      = (const float*)d_in[31];

  char* base = (char*)d_ws;
  size_t off = 0;
  auto alloc = [&](size_t nbytes) -> void* {
    void* p = base + off;
    off += (nbytes + 255) & ~(size_t)255;
    return p;
  };
  const size_t MBy = 1024 * 1024;
  u16*   Wb_bf   = (u16*)alloc((size_t)NV * NG * 2);        // 64 MB
  u16*   evecsT  = (u16*)alloc((size_t)128 * NV * 2);
  float* GXE2    = (float*)alloc((size_t)2 * NV * 128 * 4); // GXE | GYE contiguous
  float* GXE     = GXE2;
  float* GYE     = GXE2 + (size_t)NV * 128;
  float* sp      = (float*)alloc((size_t)NSLICE * 8192 * 4);
  float* Es      = (float*)alloc(8192 * 4);
  float* diffx   = (float*)alloc((size_t)NV * 64 * 4);
  float* gxb     = (float*)alloc((size_t)NG * 64 * 4);
  float* xd      = (float*)alloc((size_t)NV * 64 * 4);
  float* gf      = (float*)alloc((size_t)NV * 64 * 4);
  float* h1      = (float*)alloc((size_t)NV * 64 * 4);
  float* xw_v    = (float*)alloc((size_t)NV * 64 * 4);
  float* xw2_v   = (float*)alloc((size_t)NV * 64 * 4);
  float* xw_g    = (float*)alloc((size_t)NG * 64 * 4);
  float* xw2_g   = (float*)alloc((size_t)NG * 64 * 4);
  float* xw1     = (float*)alloc((size_t)NG * 64 * 4);
  float* xw2k    = (float*)alloc((size_t)NG * 64 * 4);
  u16*   xwgT    = (u16*)alloc((size_t)64 * NG * 2);
  u16*   xw2vT   = (u16*)alloc((size_t)64 * NV * 2);
  float* Wbp     = (float*)alloc((size_t)NV * 64 * 4);
  float* WbTp    = (float*)alloc((size_t)NG * 64 * 4);
  float* deg_v   = (float*)alloc(NV * 4);
  float* inv_deg_v = (float*)alloc(NV * 4);
  float* rsv     = (float*)alloc(NV * 4);
  float* deg_g   = (float*)alloc(NG * 4);
  float* inv_deg_g = (float*)alloc(NG * 4);
  float* rsg     = (float*)alloc(NG * 4);
  float* deg_e   = (float*)alloc(NG * 4);
  float* invdeg_e = (float*)alloc(NG * 4);
  float* dinv_e  = (float*)alloc(NG * 4);
  int*   cnt     = (int*)alloc(NG * 4);
  int*   row_ptr = (int*)alloc((NG + 1) * 4);
  int*   cursor  = (int*)alloc(NG * 4);
  int*   csr_src = (int*)alloc(NE * 4);
  float* csr_norm = (float*)alloc(NE * 4);

  // optional tiers: explicit WbT (64 MB) and larger parts for k-split
  size_t avail = ws_size > off ? ws_size - off : 0;
  u16* WbT_bf = nullptr;
  int nzHalf;
  size_t partsBytes;
  if (avail >= 129 * MBy)      { WbT_bf = (u16*)alloc((size_t)NG * NV * 2); partsBytes = 64 * MBy; nzHalf = 8; }
  else if (avail >= 97 * MBy)  { WbT_bf = (u16*)alloc((size_t)NG * NV * 2); partsBytes = 32 * MBy; nzHalf = 4; }
  else if (avail >= 81 * MBy)  { WbT_bf = (u16*)alloc((size_t)NG * NV * 2); partsBytes = 16 * MBy; nzHalf = 2; }
  else if (avail >= 33 * MBy)  { partsBytes = 32 * MBy; nzHalf = 4; }
  else                          { partsBytes = 16 * MBy; nzHalf = 2; }
  float* parts = (float*)alloc(partsBytes);
  if (off > ws_size) return;  // insufficient workspace -> fail loudly

  dim3 B256(256);

  // ---------- setup ----------
  k_fill4<<<dim3(80), B256, 0, stream>>>(deg_v, deg_g, deg_e, cnt);
  k_wb_build<<<dim3(128, 64), B256, 0, stream>>>(vertices, graph_pos, Wb_bf, WbT_bf, deg_v, deg_g);
  k_edge_prep<<<dim3(256), B256, 0, stream>>>(eidx, ew, deg_e, cnt);
  k_recips<<<dim3(64), B256, 0, stream>>>(deg_v, inv_deg_v, rsv, deg_g, inv_deg_g, rsg,
                                          deg_e, invdeg_e, dinv_e);
  k_scan<<<dim3(1), dim3(1024), 0, stream>>>(cnt, row_ptr, cursor);
  k_scatter<<<dim3(256), B256, 0, stream>>>(eidx, ew, dinv_e, cursor, csr_src, csr_norm);
  k_evecsT<<<dim3(256, 4), B256, 0, stream>>>(evecs, evecsT);
  // GXE = gradX @ evecs, GYE = gradY @ evecs (z-packed, k-split nzHalf each)
  gemm_setup<<<dim3(64, 1, 2 * nzHalf), B256, 0, stream>>>(
      gradX, gradY, evecsT, parts, nzHalf, 8192 / nzHalf);
  k_reduce2<<<dim3(2048), B256, 0, stream>>>(parts, GXE2, NV * 128, nzHalf);
  k_lin_both<<<dim3(3072), B256, 0, stream>>>(x_in, graph_x, lin1_w, lin1_b, lin2_w, lin2_b, diffx, gxb);

  // ---------- 4 blocks ----------
  for (int i = 0; i < 4; i++) {
    const float* dtrow = diff_time + i * 64;
    k_spec_part<<<dim3(128, NSLICE), dim3(64), 0, stream>>>(evecs, mass, diffx, sp);
    k_es<<<dim3(32), B256, 0, stream>>>(sp, evals, dtrow, Es);
    k_xdgf<<<dim3(2048), B256, 0, stream>>>(evecs, GXE, GYE, Es, A_re + i * 4096, A_im + i * 4096, xd, gf);
    k_mlp0<<<dim3(2048), B256, 0, stream>>>(diffx, xd, gf, mlp_w0 + i * 12288, mlp_b0 + i * 64, h1);
    k_mlp12<<<dim3(2048), B256, 0, stream>>>(h1, mlp_w1 + i * 4096, mlp_b1 + i * 64,
        mlp_w2 + i * 4096, mlp_b2 + i * 64, diffx);
    // graph GCN (2 convs) + graph-side dual projection
    k_mm64<false, false, false><<<dim3(1024), B256, 0, stream>>>(gxb, gcn1_w + i * 4096, nullptr, nullptr, xw1);
    k_aggmm<<<dim3(NG), dim3(64), 0, stream>>>(xw1, row_ptr, csr_src, csr_norm, invdeg_e,
        gcn1_b + i * 64, gcn2_w + i * 4096, xw2k);
    k_aggdual<<<dim3(NG), dim3(64), 0, stream>>>(xw2k, row_ptr, csr_src, csr_norm, invdeg_e,
        gcn2_b + i * 64, gs_w + i * 4096, sg_w + i * 4096, xw_g, xw2_g, xwgT);
    // vertex-side dual projection
    k_mm_dual<false, true><<<dim3(2048), B256, 0, stream>>>(diffx, gs_w + i * 4096, sg_w + i * 4096,
        xw_v, xw2_v, nullptr, xw2vT, NV);
    // Wbp = Wb @ xw_g  (M=NV, K=NG, ksplit 8)
    gemm_bf16<<<dim3(64, 1, 8), B256, 0, stream>>>(
        Wb_bf, NG, xwgT, NG, parts, NV, 512);
    k_reduce<<<dim3(512), B256, 0, stream>>>(parts, Wbp, NV * 64, 8);
    // WbTp = Wb^T @ xw2_v (M=NG, K=NV, ksplit 16)
    if (WbT_bf != nullptr) {
      gemm_bf16<<<dim3(32, 1, 16), B256, 0, stream>>>(
          WbT_bf, NV, xw2vT, NV, parts, NG, 512);
    } else {
      gemm_k<64, false, true><<<dim3(32, 1, 16), B256, 0, stream>>>(
          Wb_bf, nullptr, 1 << 30, xw2vT, parts, NG, 64, NG, NV, 512);
    }
    k_reduce<<<dim3(256), B256, 0, stream>>>(parts, WbTp, NG * 64, 16);
    // fused combine
    k_combine<<<dim3(3072), B256, 0, stream>>>(xw_v, Wbp, xw2_v, xw_g, WbTp, xw2_g,
        inv_deg_v, rsv, inv_deg_g, rsg, gs_b + i * 64, sg_b + i * 64, diffx, gxb);
  }

  hipMemcpyAsync(d_out, diffx, (size_t)NV * 64 * 4, hipMemcpyDeviceToDevice, stream);
}